// Round 3
// baseline (757.705 us; speedup 1.0000x reference)
//
#include <hip/hip_runtime.h>
#include <stdint.h>

#define NB   256
#define NN   343
#define CC   256
#define NH   8
#define HD   32
#define NWIN 64
#define SCALE_ 0.17677669529663689f
#define LOG2E_ 1.4426950408889634f

typedef unsigned int u32;
typedef unsigned short u16;
typedef float f4 __attribute__((ext_vector_type(4)));
typedef short s8v __attribute__((ext_vector_type(8)));
typedef short s4v __attribute__((ext_vector_type(4)));
typedef _Float16 h8 __attribute__((ext_vector_type(8)));
typedef _Float16 h4 __attribute__((ext_vector_type(4)));
typedef __fp16 pk2 __attribute__((ext_vector_type(2)));

// ws layout (bytes); total 229,077,536 (unchanged footprint)
#define OFF_Q    0ull
#define OFF_K    44957696ull           // 87808*256*2
#define OFF_V    89915392ull
#define OFF_XH   134873088ull          // now: bias/mask tables (x fp16 stage removed)
#define OFF_CTXH 179830784ull          // ctx as fp16, 45 MB
#define OFF_WT   228553248ull          // qkv_w^T fp16 [768][256]
#define OFF_PWT  228946464ull          // proj_w^T fp16 [256][256]

// tables: row-major f16, j padded to 352 with -inf
// mT[w][i][352]: 64*343*352*2 = 15,454,208 B ; bT[h][i][352]: 1,931,776 B
#define OFF_MT   OFF_XH
#define OFF_BT   (OFF_XH + 15454208ull)
#define MTW      352

__device__ __forceinline__ u16 f2bf(float f){
  u32 u = __float_as_uint(f);
  u = u + 0x7fffu + ((u >> 16) & 1u);   // RNE
  return (u16)(u >> 16);
}
__device__ __forceinline__ u16 f2h(float f){
  _Float16 h = (_Float16)f;
  return __builtin_bit_cast(u16, h);
}
__device__ __forceinline__ void cp16(const void* g, void* s){
  __builtin_amdgcn_global_load_lds(
    (const __attribute__((address_space(1))) unsigned int*)g,
    (__attribute__((address_space(3))) unsigned int*)s, 16, 0, 0);
}

// ---------------- K0c: transpose+convert weights ----------------
__global__ __launch_bounds__(256) void k_cvt_w(const float* __restrict__ qw,
                                               const float* __restrict__ pw,
                                               _Float16* __restrict__ wT,
                                               _Float16* __restrict__ pwT){
  int idx = blockIdx.x*256 + threadIdx.x;
  int row = idx >> 5;
  int k0  = (idx & 31) << 3;
  const float* src; int stride; _Float16* dst;
  if (row < 768){ src = qw + row;        stride = 768; dst = wT  + (size_t)row*256 + k0; }
  else          { src = pw + (row-768);  stride = 256; dst = pwT + (size_t)(row-768)*256 + k0; }
  ushort4 pk[2];
  u16* p = (u16*)&pk[0];
  #pragma unroll
  for (int j=0;j<8;j++) p[j] = f2h(src[(size_t)(k0+j)*stride]);
  *(uint4*)dst = *(uint4*)&pk[0];
}

// ---------------- K0d: row-major f16 bias/mask tables, -inf pad ----------------
// thread = one (tbl, i, jt): 16 cols. tbl<64: mask w; else bias h.
__global__ __launch_bounds__(256) void k_bmt(const float* __restrict__ mask,
                                             const float* __restrict__ tbl,
                                             const int* __restrict__ ridx,
                                             _Float16* __restrict__ mT,
                                             _Float16* __restrict__ bT){
  int idx = blockIdx.x*256 + threadIdx.x;
  const int tot = 72*NN*22;
  if (idx >= tot) return;
  int tb   = idx / (NN*22);
  int rest = idx - tb*(NN*22);
  int i  = rest / 22;
  int jt = rest - i*22;
  const u16 NEGINF = 0xFC00u;
  u16 buf[16];
  _Float16* dst;
  if (tb < 64){
    const float* mrow = mask + ((size_t)tb*NN + i)*NN;
    #pragma unroll
    for (int e=0;e<16;e++){
      int col = jt*16 + e;
      buf[e] = (col < NN) ? f2h(mrow[col]) : NEGINF;
    }
    dst = mT + ((size_t)tb*NN + i)*MTW + jt*16;
  } else {
    int hh = tb - 64;
    const int* rrow = ridx + (size_t)i*NN;
    #pragma unroll
    for (int e=0;e<16;e++){
      int col = jt*16 + e;
      buf[e] = (col < NN) ? f2h(tbl[rrow[col]*NH + hh]) : NEGINF;
    }
    dst = bT + ((size_t)hh*NN + i)*MTW + jt*16;
  }
  uint4* d4 = (uint4*)dst;
  uint4* s4_ = (uint4*)buf;
  d4[0] = s4_[0]; d4[1] = s4_[1];
}

// ---------------- K1: qkv GEMM, fused x f32->f16 staging ----------------
// grid = 686*6; out layout per stream: [m=87808][256] u16 (q,k bf16 / v f16)
__global__ __launch_bounds__(256,4) void k_qkv(const float* __restrict__ x,
                                               const _Float16* __restrict__ wT,
                                               const float* __restrict__ qkvb,
                                               u16* __restrict__ qws,
                                               u16* __restrict__ kws,
                                               u16* __restrict__ vws){
  const int nt = blockIdx.x % 6;
  const int mt = blockIdx.x / 6;
  const int m0 = mt*128, n0 = nt*128;
  __shared__ _Float16 As[128*32];
  __shared__ _Float16 Bs[128*32];
  const int t = threadIdx.x;
  const int wv = t >> 6, ln = t & 63, lc = ln & 15, lq = ln >> 4;
  const int wm = wv & 1, wn = wv >> 1;
  const float*    gax = x  + (size_t)(m0 + (t>>2))*CC + (t&3)*8;
  const _Float16* gb  = wT + (size_t)(n0 + (t>>2))*CC + (t&3)*8;
  f4 acc[4][4];
  #pragma unroll
  for (int i=0;i<4;i++)
    #pragma unroll
    for (int j=0;j<4;j++) acc[i][j] = (f4){0.f,0.f,0.f,0.f};
  for (int kc=0; kc<256; kc+=32){
    float4 a0 = *(const float4*)(gax + kc);
    float4 a1 = *(const float4*)(gax + kc + 4);
    float4 b0 = *(const float4*)(gax + 64*CC + kc);
    float4 b1 = *(const float4*)(gax + 64*CC + kc + 4);
    __syncthreads();
    cp16(gb + kc,          Bs + t*8);
    cp16(gb + kc + 64*CC,  Bs + 2048 + t*8);
    ushort4 pa[2], pb_[2];
    pa[0].x=f2h(a0.x); pa[0].y=f2h(a0.y); pa[0].z=f2h(a0.z); pa[0].w=f2h(a0.w);
    pa[1].x=f2h(a1.x); pa[1].y=f2h(a1.y); pa[1].z=f2h(a1.z); pa[1].w=f2h(a1.w);
    pb_[0].x=f2h(b0.x); pb_[0].y=f2h(b0.y); pb_[0].z=f2h(b0.z); pb_[0].w=f2h(b0.w);
    pb_[1].x=f2h(b1.x); pb_[1].y=f2h(b1.y); pb_[1].z=f2h(b1.z); pb_[1].w=f2h(b1.w);
    *(uint4*)(As + t*8)        = *(uint4*)&pa[0];
    *(uint4*)(As + 2048 + t*8) = *(uint4*)&pb_[0];
    __syncthreads();
    h8 af[4], bf[4];
    #pragma unroll
    for (int mi=0;mi<4;mi++) af[mi] = *(const h8*)(As + (wm*64 + mi*16 + lc)*32 + lq*8);
    #pragma unroll
    for (int ni=0;ni<4;ni++) bf[ni] = *(const h8*)(Bs + (wn*64 + ni*16 + lc)*32 + lq*8);
    #pragma unroll
    for (int mi=0;mi<4;mi++)
      #pragma unroll
      for (int ni=0;ni<4;ni++)
        acc[mi][ni] = __builtin_amdgcn_mfma_f32_16x16x32_f16(af[mi], bf[ni], acc[mi][ni], 0,0,0);
  }
  // epilogue: block-uniform stream, [m][256] coalesced-ish stores
  const int s = nt >> 1;               // 0=q 1=k 2=v
  u16* dst = (s==0) ? qws : (s==1) ? kws : vws;
  const int nc0 = (nt & 1)*128 + wn*64;
  float bias4[4];
  #pragma unroll
  for (int ni=0;ni<4;ni++) bias4[ni] = qkvb[n0 + wn*64 + ni*16 + lc];
  #pragma unroll
  for (int mi=0;mi<4;mi++){
    #pragma unroll
    for (int r=0;r<4;r++){
      int m = m0 + wm*64 + mi*16 + lq*4 + r;
      u16* row = dst + (size_t)m*CC + nc0;
      #pragma unroll
      for (int ni=0;ni<4;ni++){
        float val = acc[mi][ni][r] + bias4[ni];
        u16 o;
        if      (s == 0) o = f2bf(val*SCALE_);
        else if (s == 1) o = f2bf(val);
        else             o = f2h(val);
        row[ni*16 + lc] = o;
      }
    }
  }
}

// ---------------- K2: MFMA flash attention, swapped-QK (P^T in regs) ----------------
// grid = 2048 (b,h), block 256 (4 waves). LDS = 25344+24064+5120 = 54528 (3 blk/CU)
#define KSTR 36
#define VSTR 376
#define PSTR 40
__global__ __launch_bounds__(256,3) void k_attn(const u16* __restrict__ qws,
                                                const u16* __restrict__ kws,
                                                const u16* __restrict__ vws,
                                                const _Float16* __restrict__ mT,
                                                const _Float16* __restrict__ bT,
                                                u16* __restrict__ ctxh){
  __shared__ u16 Klds[352*KSTR];
  __shared__ u16 Vt[HD*VSTR];
  __shared__ u16 PchT[4][16*PSTR];
  const int bh = blockIdx.x;
  const int b = bh >> 3, h = bh & 7, w = b & (NWIN-1);
  const int t = threadIdx.x;
  // ---- stage K rows (bf16), zero-pad rows 343..351 ----
  for (int task = t; task < 352*4; task += 256){
    int j = task >> 2, d0 = (task & 3) << 3;
    uint4 val = {0u,0u,0u,0u};
    if (j < NN) val = *(const uint4*)(kws + ((size_t)(b*NN + j))*CC + h*HD + d0);
    *(uint2*)&Klds[j*KSTR + d0]     = make_uint2(val.x, val.y);
    *(uint2*)&Klds[j*KSTR + d0 + 4] = make_uint2(val.z, val.w);
  }
  // ---- stage V transposed: Vt[d][j], zero-pad j>=343 ----
  for (int task = t; task < 88*4; task += 256){
    int jg = task >> 2, d0 = (task & 3) << 3;
    int j0 = jg*4;
    uint4 r0={0,0,0,0}, r1={0,0,0,0}, r2={0,0,0,0}, r3={0,0,0,0};
    if (j0   < NN) r0 = *(const uint4*)(vws + ((size_t)(b*NN + j0  ))*CC + h*HD + d0);
    if (j0+1 < NN) r1 = *(const uint4*)(vws + ((size_t)(b*NN + j0+1))*CC + h*HD + d0);
    if (j0+2 < NN) r2 = *(const uint4*)(vws + ((size_t)(b*NN + j0+2))*CC + h*HD + d0);
    if (j0+3 < NN) r3 = *(const uint4*)(vws + ((size_t)(b*NN + j0+3))*CC + h*HD + d0);
    const u32* p0=(const u32*)&r0; const u32* p1=(const u32*)&r1;
    const u32* p2=(const u32*)&r2; const u32* p3=(const u32*)&r3;
    #pragma unroll
    for (int e=0;e<8;e++){
      int sh_ = (e&1)*16;
      ushort4 c4;
      c4.x = (u16)(p0[e>>1] >> sh_);
      c4.y = (u16)(p1[e>>1] >> sh_);
      c4.z = (u16)(p2[e>>1] >> sh_);
      c4.w = (u16)(p3[e>>1] >> sh_);
      *(ushort4*)&Vt[(d0+e)*VSTR + j0] = c4;
    }
  }
  __syncthreads();
  const int wv = t >> 6, ln = t & 63;
  const int lc = ln & 15, lq = ln >> 4;
  u16* pch = &PchT[wv][0];
  const f4 z4 = {0.f,0.f,0.f,0.f};
  for (int sub = wv; sub < 22; sub += 4){
    int qrow = sub*16 + lc; if (qrow > NN-1) qrow = NN-1;
    // B-frag: Q row i = lc-indexed
    s8v qa = *(const s8v*)(qws + ((size_t)(b*NN + qrow))*CC + h*HD + lq*8);
    const _Float16* mrow = mT + ((size_t)w*NN + qrow)*MTW;
    const _Float16* brow = bT + ((size_t)h*NN + qrow)*MTW;
    // preload half the combined bias+mask cols (VGPR-bounded)
    h4 sh[11];
    #pragma unroll
    for (int jt=0; jt<11; jt++)
      sh[jt] = *(const h4*)(mrow + jt*16 + lq*4) + *(const h4*)(brow + jt*16 + lq*4);
    // QK^T swapped: D[j][i], j = jt*16+lq*4+r, i = sub*16+lc
    f4 acc[22];
    #pragma unroll
    for (int jt=0; jt<22; jt++){
      const u16* kp = &Klds[(jt*16+lc)*KSTR + lq*8];
      s4v k0 = *(const s4v*)kp;
      s4v k1 = *(const s4v*)(kp+4);
      s8v bk = {k0[0],k0[1],k0[2],k0[3],k1[0],k1[1],k1[2],k1[3]};
      acc[jt] = __builtin_amdgcn_mfma_f32_16x16x32_bf16(bk, qa, z4, 0,0,0);
    }
    // bias+mask add + running max (per i = lc; in-lane over j)
    float mx0=-INFINITY, mx1=-INFINITY, mx2=-INFINITY, mx3=-INFINITY;
    #pragma unroll
    for (int jt=0; jt<22; jt++){
      h4 sv4 = (jt < 11) ? sh[jt]
             : (*(const h4*)(mrow + jt*16 + lq*4) + *(const h4*)(brow + jt*16 + lq*4));
      float v0 = acc[jt][0] + (float)sv4[0];
      float v1 = acc[jt][1] + (float)sv4[1];
      float v2 = acc[jt][2] + (float)sv4[2];
      float v3 = acc[jt][3] + (float)sv4[3];
      acc[jt] = (f4){v0,v1,v2,v3};
      mx0 = fmaxf(mx0, v0); mx1 = fmaxf(mx1, v1);
      mx2 = fmaxf(mx2, v2); mx3 = fmaxf(mx3, v3);
    }
    float mx = fmaxf(fmaxf(mx0,mx1), fmaxf(mx2,mx3));
    mx = fmaxf(mx, __shfl_xor(mx, 16));
    mx = fmaxf(mx, __shfl_xor(mx, 32));
    float mxl = mx * LOG2E_;
    // exp + sum
    f4 ps = z4;
    #pragma unroll
    for (int jt=0; jt<22; jt++){
      f4 a = acc[jt];
      a[0] = exp2f(__builtin_fmaf(a[0], LOG2E_, -mxl));
      a[1] = exp2f(__builtin_fmaf(a[1], LOG2E_, -mxl));
      a[2] = exp2f(__builtin_fmaf(a[2], LOG2E_, -mxl));
      a[3] = exp2f(__builtin_fmaf(a[3], LOG2E_, -mxl));
      acc[jt] = a;
      ps += a;
    }
    float l = (ps[0]+ps[1]) + (ps[2]+ps[3]);
    l += __shfl_xor(l, 16);
    l += __shfl_xor(l, 32);
    float inv = __builtin_amdgcn_rcpf(l);
    // PV: O^T[d][i] += V^T[d][j] * P^T[j][i]
    f4 o0 = z4, o1 = z4;
    #pragma unroll
    for (int kt=0; kt<11; kt++){
      int ja = kt*2, jb = kt*2+1;
      u32 w0 = __builtin_bit_cast(u32, __builtin_amdgcn_cvt_pkrtz(acc[ja][0], acc[ja][1]));
      u32 w1 = __builtin_bit_cast(u32, __builtin_amdgcn_cvt_pkrtz(acc[ja][2], acc[ja][3]));
      u32 w2 = __builtin_bit_cast(u32, __builtin_amdgcn_cvt_pkrtz(acc[jb][0], acc[jb][1]));
      u32 w3 = __builtin_bit_cast(u32, __builtin_amdgcn_cvt_pkrtz(acc[jb][2], acc[jb][3]));
      *(uint2*)(pch + lc*PSTR + lq*4)      = make_uint2(w0, w1);
      *(uint2*)(pch + lc*PSTR + 16 + lq*4) = make_uint2(w2, w3);
      h8 pb = *(const h8*)((const _Float16*)pch + lc*PSTR + lq*8);
      h8 va0 = *(const h8*)((const _Float16*)&Vt[(lc   )*VSTR + kt*32 + lq*8]);
      h8 va1 = *(const h8*)((const _Float16*)&Vt[(lc+16)*VSTR + kt*32 + lq*8]);
      o0 = __builtin_amdgcn_mfma_f32_16x16x32_f16(va0, pb, o0, 0,0,0);
      o1 = __builtin_amdgcn_mfma_f32_16x16x32_f16(va1, pb, o1, 0,0,0);
    }
    // write: lane owns row i=lc, d = lq*4+r (+16)
    int i = sub*16 + lc;
    if (i < NN){
      u16* op = ctxh + ((size_t)(b*NN + i))*CC + h*HD;
      u32 q0 = (u32)f2h(o0[0]*inv) | ((u32)f2h(o0[1]*inv) << 16);
      u32 q1 = (u32)f2h(o0[2]*inv) | ((u32)f2h(o0[3]*inv) << 16);
      u32 q2 = (u32)f2h(o1[0]*inv) | ((u32)f2h(o1[1]*inv) << 16);
      u32 q3 = (u32)f2h(o1[2]*inv) | ((u32)f2h(o1[3]*inv) << 16);
      *(uint2*)(op + lq*4)      = make_uint2(q0, q1);
      *(uint2*)(op + 16 + lq*4) = make_uint2(q2, q3);
    }
  }
}

// ---------------- K3: proj GEMM via fp16 MFMA ----------------
__global__ __launch_bounds__(256,4) void k_proj(const _Float16* __restrict__ ctxh,
                                                const _Float16* __restrict__ pwT,
                                                const float* __restrict__ pb,
                                                float* __restrict__ out){
  const int nt = blockIdx.x & 1;
  const int mt = blockIdx.x >> 1;
  const int m0 = mt*128, n0 = nt*128;
  __shared__ _Float16 As[128*32];
  __shared__ _Float16 Bs[128*32];
  const int t = threadIdx.x;
  const int wv = t >> 6, ln = t & 63, lc = ln & 15, lq = ln >> 4;
  const int wm = wv & 1, wn = wv >> 1;
  const _Float16* ga = ctxh + (size_t)(m0 + (t>>2))*CC + (t&3)*8;
  const _Float16* gb = pwT  + (size_t)(n0 + (t>>2))*CC + (t&3)*8;
  f4 acc[4][4];
  #pragma unroll
  for (int i=0;i<4;i++)
    #pragma unroll
    for (int j=0;j<4;j++) acc[i][j] = (f4){0.f,0.f,0.f,0.f};
  for (int kc=0; kc<256; kc+=32){
    __syncthreads();
    cp16(ga + kc,          As + t*8);
    cp16(ga + kc + 64*CC,  As + 2048 + t*8);
    cp16(gb + kc,          Bs + t*8);
    cp16(gb + kc + 64*CC,  Bs + 2048 + t*8);
    __syncthreads();
    h8 af[4], bf[4];
    #pragma unroll
    for (int mi=0;mi<4;mi++) af[mi] = *(const h8*)(As + (wm*64 + mi*16 + lc)*32 + lq*8);
    #pragma unroll
    for (int ni=0;ni<4;ni++) bf[ni] = *(const h8*)(Bs + (wn*64 + ni*16 + lc)*32 + lq*8);
    #pragma unroll
    for (int mi=0;mi<4;mi++)
      #pragma unroll
      for (int ni=0;ni<4;ni++)
        acc[mi][ni] = __builtin_amdgcn_mfma_f32_16x16x32_f16(af[mi], bf[ni], acc[mi][ni], 0,0,0);
  }
  float bias4[4];
  #pragma unroll
  for (int ni=0;ni<4;ni++) bias4[ni] = pb[n0 + wn*64 + ni*16 + lc];
  #pragma unroll
  for (int mi=0;mi<4;mi++){
    #pragma unroll
    for (int r=0;r<4;r++){
      int m = m0 + wm*64 + mi*16 + lq*4 + r;
      float* orow = out + (size_t)m*CC + n0 + wn*64;
      #pragma unroll
      for (int ni=0;ni<4;ni++)
        orow[ni*16 + lc] = acc[mi][ni][r] + bias4[ni];
    }
  }
}

extern "C" void kernel_launch(void* const* d_in, const int* in_sizes, int n_in,
                              void* d_out, int out_size, void* d_ws, size_t ws_size,
                              hipStream_t stream){
  (void)in_sizes; (void)n_in; (void)out_size; (void)ws_size;
  const float* x   = (const float*)d_in[0];
  const float* msk = (const float*)d_in[1];
  const float* qw  = (const float*)d_in[2];
  const float* qb  = (const float*)d_in[3];
  const float* pw  = (const float*)d_in[4];
  const float* pb  = (const float*)d_in[5];
  const float* tbl = (const float*)d_in[6];
  const int*   rix = (const int*)d_in[7];
  float* out = (float*)d_out;
  char* ws = (char*)d_ws;
  u16*      qws    = (u16*)(ws + OFF_Q);
  u16*      kws    = (u16*)(ws + OFF_K);
  u16*      vws    = (u16*)(ws + OFF_V);
  _Float16* ctxh   = (_Float16*)(ws + OFF_CTXH);
  _Float16* wT     = (_Float16*)(ws + OFF_WT);
  _Float16* pwT    = (_Float16*)(ws + OFF_PWT);
  _Float16* mT     = (_Float16*)(ws + OFF_MT);
  _Float16* bT     = (_Float16*)(ws + OFF_BT);

  hipLaunchKernelGGL(k_cvt_w, dim3(128), dim3(256), 0, stream, qw, pw, wT, pwT);
  hipLaunchKernelGGL(k_bmt,   dim3((72*NN*22 + 255)/256), dim3(256), 0, stream, msk, tbl, rix, mT, bT);
  hipLaunchKernelGGL(k_qkv,   dim3(686*6), dim3(256), 0, stream, x, wT, qb, qws, kws, vws);
  hipLaunchKernelGGL(k_attn,  dim3(NB*NH), dim3(256), 0, stream, qws, kws, vws, mT, bT, (u16*)ctxh);
  hipLaunchKernelGGL(k_proj,  dim3(686*2), dim3(256), 0, stream, ctxh, pwT, pb, out);
}

// Round 4
// 681.604 us; speedup vs baseline: 1.1116x; 1.1116x over previous
//
#include <hip/hip_runtime.h>
#include <stdint.h>

#define NB   256
#define NN   343
#define CC   256
#define NH   8
#define HD   32
#define NWIN 64
#define SCALE_ 0.17677669529663689f
#define LOG2E_ 1.4426950408889634f

typedef unsigned int u32;
typedef unsigned short u16;
typedef float f4 __attribute__((ext_vector_type(4)));
typedef short s8v __attribute__((ext_vector_type(8)));
typedef short s4v __attribute__((ext_vector_type(4)));
typedef _Float16 h8 __attribute__((ext_vector_type(8)));
typedef _Float16 h4 __attribute__((ext_vector_type(4)));

// ws layout (bytes); total 229,077,536 (unchanged footprint)
#define OFF_Q    0ull
#define OFF_K    44957696ull           // 87808*256*2
#define OFF_V    89915392ull
#define OFF_XH   134873088ull          // bias/mask tables live here
#define OFF_CTXH 179830784ull          // ctx as fp16, 45 MB
#define OFF_WT   228553248ull          // qkv_w^T fp16 [768][256]
#define OFF_PWT  228946464ull          // proj_w^T fp16 [256][256]

// tables: row-major f16, j padded to 352 with -inf
// mT[w][i][352]: 64*343*352*2 = 15,454,208 B ; bT[h][i][352]: 1,931,776 B
#define OFF_MT   OFF_XH
#define OFF_BT   (OFF_XH + 15454208ull)
#define MTW      352

__device__ __forceinline__ u16 f2bf(float f){
  u32 u = __float_as_uint(f);
  u = u + 0x7fffu + ((u >> 16) & 1u);   // RNE
  return (u16)(u >> 16);
}
__device__ __forceinline__ u16 f2h(float f){
  _Float16 h = (_Float16)f;
  return __builtin_bit_cast(u16, h);
}
__device__ __forceinline__ void cp16(const void* g, void* s){
  __builtin_amdgcn_global_load_lds(
    (const __attribute__((address_space(1))) unsigned int*)g,
    (__attribute__((address_space(3))) unsigned int*)s, 16, 0, 0);
}

// ---------------- K0c: transpose+convert weights ----------------
__global__ __launch_bounds__(256) void k_cvt_w(const float* __restrict__ qw,
                                               const float* __restrict__ pw,
                                               _Float16* __restrict__ wT,
                                               _Float16* __restrict__ pwT){
  int idx = blockIdx.x*256 + threadIdx.x;
  int row = idx >> 5;
  int k0  = (idx & 31) << 3;
  const float* src; int stride; _Float16* dst;
  if (row < 768){ src = qw + row;        stride = 768; dst = wT  + (size_t)row*256 + k0; }
  else          { src = pw + (row-768);  stride = 256; dst = pwT + (size_t)(row-768)*256 + k0; }
  ushort4 pk[2];
  u16* p = (u16*)&pk[0];
  #pragma unroll
  for (int j=0;j<8;j++) p[j] = f2h(src[(size_t)(k0+j)*stride]);
  *(uint4*)dst = *(uint4*)&pk[0];
}

// ---------------- K0d: row-major f16 bias/mask tables, -inf pad ----------------
__global__ __launch_bounds__(256) void k_bmt(const float* __restrict__ mask,
                                             const float* __restrict__ tbl,
                                             const int* __restrict__ ridx,
                                             _Float16* __restrict__ mT,
                                             _Float16* __restrict__ bT){
  int idx = blockIdx.x*256 + threadIdx.x;
  const int tot = 72*NN*22;
  if (idx >= tot) return;
  int tb   = idx / (NN*22);
  int rest = idx - tb*(NN*22);
  int i  = rest / 22;
  int jt = rest - i*22;
  const u16 NEGINF = 0xFC00u;
  u16 buf[16];
  _Float16* dst;
  if (tb < 64){
    const float* mrow = mask + ((size_t)tb*NN + i)*NN;
    #pragma unroll
    for (int e=0;e<16;e++){
      int col = jt*16 + e;
      buf[e] = (col < NN) ? f2h(mrow[col]) : NEGINF;
    }
    dst = mT + ((size_t)tb*NN + i)*MTW + jt*16;
  } else {
    int hh = tb - 64;
    const int* rrow = ridx + (size_t)i*NN;
    #pragma unroll
    for (int e=0;e<16;e++){
      int col = jt*16 + e;
      buf[e] = (col < NN) ? f2h(tbl[rrow[col]*NH + hh]) : NEGINF;
    }
    dst = bT + ((size_t)hh*NN + i)*MTW + jt*16;
  }
  uint4* d4 = (uint4*)dst;
  uint4* s4_ = (uint4*)buf;
  d4[0] = s4_[0]; d4[1] = s4_[1];
}

// ---------------- K1: qkv GEMM, fused x f32->f16 staging ----------------
// grid = 686*6; output layout per stream: [bh][343][32] u16 (q,k bf16 / v f16)
__global__ __launch_bounds__(256,4) void k_qkv(const float* __restrict__ x,
                                               const _Float16* __restrict__ wT,
                                               const float* __restrict__ qkvb,
                                               u16* __restrict__ qws,
                                               u16* __restrict__ kws,
                                               u16* __restrict__ vws){
  const int nt = blockIdx.x % 6;
  const int mt = blockIdx.x / 6;
  const int m0 = mt*128, n0 = nt*128;
  __shared__ _Float16 As[128*32];
  __shared__ _Float16 Bs[128*32];
  const int t = threadIdx.x;
  const int wv = t >> 6, ln = t & 63, lc = ln & 15, lq = ln >> 4;
  const int wm = wv & 1, wn = wv >> 1;
  const float*    gax = x  + (size_t)(m0 + (t>>2))*CC + (t&3)*8;
  const _Float16* gb  = wT + (size_t)(n0 + (t>>2))*CC + (t&3)*8;
  f4 acc[4][4];
  #pragma unroll
  for (int i=0;i<4;i++)
    #pragma unroll
    for (int j=0;j<4;j++) acc[i][j] = (f4){0.f,0.f,0.f,0.f};
  for (int kc=0; kc<256; kc+=32){
    float4 a0 = *(const float4*)(gax + kc);
    float4 a1 = *(const float4*)(gax + kc + 4);
    float4 b0 = *(const float4*)(gax + 64*CC + kc);
    float4 b1 = *(const float4*)(gax + 64*CC + kc + 4);
    __syncthreads();
    cp16(gb + kc,          Bs + t*8);
    cp16(gb + kc + 64*CC,  Bs + 2048 + t*8);
    ushort4 pa[2], pb_[2];
    pa[0].x=f2h(a0.x); pa[0].y=f2h(a0.y); pa[0].z=f2h(a0.z); pa[0].w=f2h(a0.w);
    pa[1].x=f2h(a1.x); pa[1].y=f2h(a1.y); pa[1].z=f2h(a1.z); pa[1].w=f2h(a1.w);
    pb_[0].x=f2h(b0.x); pb_[0].y=f2h(b0.y); pb_[0].z=f2h(b0.z); pb_[0].w=f2h(b0.w);
    pb_[1].x=f2h(b1.x); pb_[1].y=f2h(b1.y); pb_[1].z=f2h(b1.z); pb_[1].w=f2h(b1.w);
    *(uint4*)(As + t*8)        = *(uint4*)&pa[0];
    *(uint4*)(As + 2048 + t*8) = *(uint4*)&pb_[0];
    __syncthreads();
    h8 af[4], bf[4];
    #pragma unroll
    for (int mi=0;mi<4;mi++) af[mi] = *(const h8*)(As + (wm*64 + mi*16 + lc)*32 + lq*8);
    #pragma unroll
    for (int ni=0;ni<4;ni++) bf[ni] = *(const h8*)(Bs + (wn*64 + ni*16 + lc)*32 + lq*8);
    #pragma unroll
    for (int mi=0;mi<4;mi++)
      #pragma unroll
      for (int ni=0;ni<4;ni++)
        acc[mi][ni] = __builtin_amdgcn_mfma_f32_16x16x32_f16(af[mi], bf[ni], acc[mi][ni], 0,0,0);
  }
  // epilogue: stream s and head h are block/ni-uniform; [bh][i][d] layout stores
  const int s = nt >> 1;               // 0=q 1=k 2=v
  u16* dst = (s==0) ? qws : (s==1) ? kws : vws;
  float bias4[4];
  #pragma unroll
  for (int ni=0;ni<4;ni++) bias4[ni] = qkvb[n0 + wn*64 + ni*16 + lc];
  #pragma unroll
  for (int mi=0;mi<4;mi++){
    #pragma unroll
    for (int r=0;r<4;r++){
      int m = m0 + wm*64 + mi*16 + lq*4 + r;
      int b = m / NN;
      int i = m - b*NN;
      #pragma unroll
      for (int ni=0;ni<4;ni++){
        int hh = (nt&1)*4 + wn*2 + (ni>>1);   // head, uniform per (block,wave,ni)
        int d0 = (ni&1)*16;
        float val = acc[mi][ni][r] + bias4[ni];
        u16 o;
        if      (s == 0) o = f2bf(val*SCALE_);
        else if (s == 1) o = f2bf(val);
        else             o = f2h(val);
        dst[((size_t)(b*NH + hh)*NN + i)*HD + d0 + lc] = o;
      }
    }
  }
}

// ---------------- K2: MFMA flash attention, swapped-QK (P^T in regs) ----------------
// grid = 2048 (b,h), block 256 (4 waves). LDS = 25344+23296+4608 = 53248 (3 blk/CU)
#define KSTR 36
#define VSTR 364
#define PSTR 36
__global__ __launch_bounds__(256,3) void k_attn(const u16* __restrict__ qws,
                                                const u16* __restrict__ kws,
                                                const u16* __restrict__ vws,
                                                const _Float16* __restrict__ mT,
                                                const _Float16* __restrict__ bT,
                                                u16* __restrict__ ctxh){
  __shared__ u16 Klds[352*KSTR];
  __shared__ u16 Vt[HD*VSTR];
  __shared__ u16 PchT[4][16*PSTR];
  const int bh = blockIdx.x;
  const int b = bh >> 3, h = bh & 7, w = b & (NWIN-1);
  const size_t kvbase = (size_t)bh * (NN*HD);
  const int t = threadIdx.x;
  // ---- stage K rows (bf16), zero-pad rows 343..351 ----
  for (int task = t; task < 352*4; task += 256){
    int j = task >> 2, d0 = (task & 3) << 3;
    uint4 val = {0u,0u,0u,0u};
    if (j < NN) val = *(const uint4*)(kws + kvbase + j*HD + d0);
    *(uint2*)&Klds[j*KSTR + d0]     = make_uint2(val.x, val.y);
    *(uint2*)&Klds[j*KSTR + d0 + 4] = make_uint2(val.z, val.w);
  }
  // ---- stage V transposed: Vt[d][j], zero-pad j>=343 ----
  for (int task = t; task < 88*4; task += 256){
    int jg = task >> 2, d0 = (task & 3) << 3;
    int j0 = jg*4;
    uint4 r0={0,0,0,0}, r1={0,0,0,0}, r2={0,0,0,0}, r3={0,0,0,0};
    const u16* vsrc = vws + kvbase;
    if (j0   < NN) r0 = *(const uint4*)(vsrc + (size_t)(j0  )*HD + d0);
    if (j0+1 < NN) r1 = *(const uint4*)(vsrc + (size_t)(j0+1)*HD + d0);
    if (j0+2 < NN) r2 = *(const uint4*)(vsrc + (size_t)(j0+2)*HD + d0);
    if (j0+3 < NN) r3 = *(const uint4*)(vsrc + (size_t)(j0+3)*HD + d0);
    const u32* p0=(const u32*)&r0; const u32* p1=(const u32*)&r1;
    const u32* p2=(const u32*)&r2; const u32* p3=(const u32*)&r3;
    #pragma unroll
    for (int e=0;e<8;e++){
      int sh_ = (e&1)*16;
      ushort4 c4;
      c4.x = (u16)(p0[e>>1] >> sh_);
      c4.y = (u16)(p1[e>>1] >> sh_);
      c4.z = (u16)(p2[e>>1] >> sh_);
      c4.w = (u16)(p3[e>>1] >> sh_);
      *(ushort4*)&Vt[(d0+e)*VSTR + j0] = c4;
    }
  }
  __syncthreads();
  const int wv = t >> 6, ln = t & 63;
  const int lc = ln & 15, lq = ln >> 4;
  u16* pch = &PchT[wv][0];
  const f4 z4 = {0.f,0.f,0.f,0.f};
  for (int sub = wv; sub < 22; sub += 4){
    int qrow = sub*16 + lc; if (qrow > NN-1) qrow = NN-1;
    // B-frag: Q row i = lc-indexed
    s8v qa = *(const s8v*)(qws + kvbase + (size_t)qrow*HD + lq*8);
    const _Float16* mrow = mT + ((size_t)w*NN + qrow)*MTW;
    const _Float16* brow = bT + ((size_t)h*NN + qrow)*MTW;
    // preload half the combined bias+mask cols (VGPR-bounded)
    h4 sh[11];
    #pragma unroll
    for (int jt=0; jt<11; jt++)
      sh[jt] = *(const h4*)(mrow + jt*16 + lq*4) + *(const h4*)(brow + jt*16 + lq*4);
    // QK^T swapped: D[j][i], j = jt*16+lq*4+r, i = sub*16+lc
    f4 acc[22];
    #pragma unroll
    for (int jt=0; jt<22; jt++){
      const u16* kp = &Klds[(jt*16+lc)*KSTR + lq*8];
      s4v k0 = *(const s4v*)kp;
      s4v k1 = *(const s4v*)(kp+4);
      s8v bk = {k0[0],k0[1],k0[2],k0[3],k1[0],k1[1],k1[2],k1[3]};
      acc[jt] = __builtin_amdgcn_mfma_f32_16x16x32_bf16(bk, qa, z4, 0,0,0);
    }
    // bias+mask add + running max (per i = lc; in-lane over j)
    float mx0=-INFINITY, mx1=-INFINITY, mx2=-INFINITY, mx3=-INFINITY;
    #pragma unroll
    for (int jt=0; jt<22; jt++){
      h4 sv4 = (jt < 11) ? sh[jt]
             : (*(const h4*)(mrow + jt*16 + lq*4) + *(const h4*)(brow + jt*16 + lq*4));
      float v0 = acc[jt][0] + (float)sv4[0];
      float v1 = acc[jt][1] + (float)sv4[1];
      float v2 = acc[jt][2] + (float)sv4[2];
      float v3 = acc[jt][3] + (float)sv4[3];
      acc[jt] = (f4){v0,v1,v2,v3};
      mx0 = fmaxf(mx0, v0); mx1 = fmaxf(mx1, v1);
      mx2 = fmaxf(mx2, v2); mx3 = fmaxf(mx3, v3);
    }
    float mx = fmaxf(fmaxf(mx0,mx1), fmaxf(mx2,mx3));
    mx = fmaxf(mx, __shfl_xor(mx, 16));
    mx = fmaxf(mx, __shfl_xor(mx, 32));
    float mxl = mx * LOG2E_;
    // exp + sum
    f4 ps = z4;
    #pragma unroll
    for (int jt=0; jt<22; jt++){
      f4 a = acc[jt];
      a[0] = exp2f(__builtin_fmaf(a[0], LOG2E_, -mxl));
      a[1] = exp2f(__builtin_fmaf(a[1], LOG2E_, -mxl));
      a[2] = exp2f(__builtin_fmaf(a[2], LOG2E_, -mxl));
      a[3] = exp2f(__builtin_fmaf(a[3], LOG2E_, -mxl));
      acc[jt] = a;
      ps += a;
    }
    float l = (ps[0]+ps[1]) + (ps[2]+ps[3]);
    l += __shfl_xor(l, 16);
    l += __shfl_xor(l, 32);
    float inv = __builtin_amdgcn_rcpf(l);
    // PV: O^T[d][i] += V^T[d][j] * P^T[j][i]
    f4 o0 = z4, o1 = z4;
    #pragma unroll
    for (int kt=0; kt<11; kt++){
      int ja = kt*2, jb = kt*2+1;
      u32 w0 = __builtin_bit_cast(u32, __builtin_amdgcn_cvt_pkrtz(acc[ja][0], acc[ja][1]));
      u32 w1 = __builtin_bit_cast(u32, __builtin_amdgcn_cvt_pkrtz(acc[ja][2], acc[ja][3]));
      u32 w2 = __builtin_bit_cast(u32, __builtin_amdgcn_cvt_pkrtz(acc[jb][0], acc[jb][1]));
      u32 w3 = __builtin_bit_cast(u32, __builtin_amdgcn_cvt_pkrtz(acc[jb][2], acc[jb][3]));
      *(uint2*)(pch + lc*PSTR + lq*4)      = make_uint2(w0, w1);
      *(uint2*)(pch + lc*PSTR + 16 + lq*4) = make_uint2(w2, w3);
      h8 pb = *(const h8*)((const _Float16*)pch + lc*PSTR + lq*8);
      h8 va0 = *(const h8*)((const _Float16*)&Vt[(lc   )*VSTR + kt*32 + lq*8]);
      h8 va1 = *(const h8*)((const _Float16*)&Vt[(lc+16)*VSTR + kt*32 + lq*8]);
      o0 = __builtin_amdgcn_mfma_f32_16x16x32_f16(va0, pb, o0, 0,0,0);
      o1 = __builtin_amdgcn_mfma_f32_16x16x32_f16(va1, pb, o1, 0,0,0);
    }
    // write: lane owns row i=lc, d = lq*4+r (+16)
    int i = sub*16 + lc;
    if (i < NN){
      u16* op = ctxh + ((size_t)(b*NN + i))*CC + h*HD;
      u32 q0 = (u32)f2h(o0[0]*inv) | ((u32)f2h(o0[1]*inv) << 16);
      u32 q1 = (u32)f2h(o0[2]*inv) | ((u32)f2h(o0[3]*inv) << 16);
      u32 q2 = (u32)f2h(o1[0]*inv) | ((u32)f2h(o1[1]*inv) << 16);
      u32 q3 = (u32)f2h(o1[2]*inv) | ((u32)f2h(o1[3]*inv) << 16);
      *(uint2*)(op + lq*4)      = make_uint2(q0, q1);
      *(uint2*)(op + 16 + lq*4) = make_uint2(q2, q3);
    }
  }
}

// ---------------- K3: proj GEMM via fp16 MFMA ----------------
__global__ __launch_bounds__(256,4) void k_proj(const _Float16* __restrict__ ctxh,
                                                const _Float16* __restrict__ pwT,
                                                const float* __restrict__ pb,
                                                float* __restrict__ out){
  const int nt = blockIdx.x & 1;
  const int mt = blockIdx.x >> 1;
  const int m0 = mt*128, n0 = nt*128;
  __shared__ _Float16 As[128*32];
  __shared__ _Float16 Bs[128*32];
  const int t = threadIdx.x;
  const int wv = t >> 6, ln = t & 63, lc = ln & 15, lq = ln >> 4;
  const int wm = wv & 1, wn = wv >> 1;
  const _Float16* ga = ctxh + (size_t)(m0 + (t>>2))*CC + (t&3)*8;
  const _Float16* gb = pwT  + (size_t)(n0 + (t>>2))*CC + (t&3)*8;
  f4 acc[4][4];
  #pragma unroll
  for (int i=0;i<4;i++)
    #pragma unroll
    for (int j=0;j<4;j++) acc[i][j] = (f4){0.f,0.f,0.f,0.f};
  for (int kc=0; kc<256; kc+=32){
    __syncthreads();
    cp16(ga + kc,          As + t*8);
    cp16(ga + kc + 64*CC,  As + 2048 + t*8);
    cp16(gb + kc,          Bs + t*8);
    cp16(gb + kc + 64*CC,  Bs + 2048 + t*8);
    __syncthreads();
    h8 af[4], bf[4];
    #pragma unroll
    for (int mi=0;mi<4;mi++) af[mi] = *(const h8*)(As + (wm*64 + mi*16 + lc)*32 + lq*8);
    #pragma unroll
    for (int ni=0;ni<4;ni++) bf[ni] = *(const h8*)(Bs + (wn*64 + ni*16 + lc)*32 + lq*8);
    #pragma unroll
    for (int mi=0;mi<4;mi++)
      #pragma unroll
      for (int ni=0;ni<4;ni++)
        acc[mi][ni] = __builtin_amdgcn_mfma_f32_16x16x32_f16(af[mi], bf[ni], acc[mi][ni], 0,0,0);
  }
  float bias4[4];
  #pragma unroll
  for (int ni=0;ni<4;ni++) bias4[ni] = pb[n0 + wn*64 + ni*16 + lc];
  #pragma unroll
  for (int mi=0;mi<4;mi++){
    #pragma unroll
    for (int r=0;r<4;r++){
      int m = m0 + wm*64 + mi*16 + lq*4 + r;
      float* orow = out + (size_t)m*CC + n0 + wn*64;
      #pragma unroll
      for (int ni=0;ni<4;ni++)
        orow[ni*16 + lc] = acc[mi][ni][r] + bias4[ni];
    }
  }
}

extern "C" void kernel_launch(void* const* d_in, const int* in_sizes, int n_in,
                              void* d_out, int out_size, void* d_ws, size_t ws_size,
                              hipStream_t stream){
  (void)in_sizes; (void)n_in; (void)out_size; (void)ws_size;
  const float* x   = (const float*)d_in[0];
  const float* msk = (const float*)d_in[1];
  const float* qw  = (const float*)d_in[2];
  const float* qb  = (const float*)d_in[3];
  const float* pw  = (const float*)d_in[4];
  const float* pb  = (const float*)d_in[5];
  const float* tbl = (const float*)d_in[6];
  const int*   rix = (const int*)d_in[7];
  float* out = (float*)d_out;
  char* ws = (char*)d_ws;
  u16*      qws    = (u16*)(ws + OFF_Q);
  u16*      kws    = (u16*)(ws + OFF_K);
  u16*      vws    = (u16*)(ws + OFF_V);
  _Float16* ctxh   = (_Float16*)(ws + OFF_CTXH);
  _Float16* wT     = (_Float16*)(ws + OFF_WT);
  _Float16* pwT    = (_Float16*)(ws + OFF_PWT);
  _Float16* mT     = (_Float16*)(ws + OFF_MT);
  _Float16* bT     = (_Float16*)(ws + OFF_BT);

  hipLaunchKernelGGL(k_cvt_w, dim3(128), dim3(256), 0, stream, qw, pw, wT, pwT);
  hipLaunchKernelGGL(k_bmt,   dim3((72*NN*22 + 255)/256), dim3(256), 0, stream, msk, tbl, rix, mT, bT);
  hipLaunchKernelGGL(k_qkv,   dim3(686*6), dim3(256), 0, stream, x, wT, qb, qws, kws, vws);
  hipLaunchKernelGGL(k_attn,  dim3(NB*NH), dim3(256), 0, stream, qws, kws, vws, mT, bT, (u16*)ctxh);
  hipLaunchKernelGGL(k_proj,  dim3(686*2), dim3(256), 0, stream, ctxh, pwT, pb, out);
}

// Round 5
// 676.356 us; speedup vs baseline: 1.1203x; 1.0078x over previous
//
#include <hip/hip_runtime.h>
#include <stdint.h>

#define NB   256
#define NN   343
#define CC   256
#define NH   8
#define HD   32
#define NWIN 64
#define SCALE_ 0.17677669529663689f
#define LOG2E_ 1.4426950408889634f

typedef unsigned int u32;
typedef unsigned short u16;
typedef float f4 __attribute__((ext_vector_type(4)));
typedef short s8v __attribute__((ext_vector_type(8)));
typedef short s4v __attribute__((ext_vector_type(4)));
typedef _Float16 h8 __attribute__((ext_vector_type(8)));
typedef _Float16 h4 __attribute__((ext_vector_type(4)));

// ws layout (bytes); total 229,077,536 (unchanged footprint)
#define OFF_Q    0ull
#define OFF_K    44957696ull           // 87808*256*2
#define OFF_V    89915392ull
#define OFF_XH   134873088ull          // bias/mask tables live here
#define OFF_CTXH 179830784ull          // ctx as fp16, 45 MB
#define OFF_WT   228553248ull          // qkv_w^T fp16 [768][256]
#define OFF_PWT  228946464ull          // proj_w^T fp16 [256][256]

// tables, lane-contiguous layout: tab[slab][i][lq][p][e] f16 where
// logical col = (2p + (e>>2))*16 + lq*4 + (e&3), p=0..10, e=0..7 (88 per lq)
// mT: 64*343*352*2 = 15,454,208 B ; bT: 8*343*352*2 = 1,931,776 B
#define OFF_MT   OFF_XH
#define OFF_BT   (OFF_XH + 15454208ull)

__device__ __forceinline__ u16 f2bf(float f){
  u32 u = __float_as_uint(f);
  u = u + 0x7fffu + ((u >> 16) & 1u);   // RNE
  return (u16)(u >> 16);
}
__device__ __forceinline__ u16 f2h(float f){
  _Float16 h = (_Float16)f;
  return __builtin_bit_cast(u16, h);
}
__device__ __forceinline__ void cp16(const void* g, void* s){
  __builtin_amdgcn_global_load_lds(
    (const __attribute__((address_space(1))) unsigned int*)g,
    (__attribute__((address_space(3))) unsigned int*)s, 16, 0, 0);
}

// ---------------- K0c: transpose+convert weights ----------------
__global__ __launch_bounds__(256) void k_cvt_w(const float* __restrict__ qw,
                                               const float* __restrict__ pw,
                                               _Float16* __restrict__ wT,
                                               _Float16* __restrict__ pwT){
  int idx = blockIdx.x*256 + threadIdx.x;
  int row = idx >> 5;
  int k0  = (idx & 31) << 3;
  const float* src; int stride; _Float16* dst;
  if (row < 768){ src = qw + row;        stride = 768; dst = wT  + (size_t)row*256 + k0; }
  else          { src = pw + (row-768);  stride = 256; dst = pwT + (size_t)(row-768)*256 + k0; }
  ushort4 pk[2];
  u16* p = (u16*)&pk[0];
  #pragma unroll
  for (int j=0;j<8;j++) p[j] = f2h(src[(size_t)(k0+j)*stride]);
  *(uint4*)dst = *(uint4*)&pk[0];
}

// ---------------- K0d: lane-contiguous f16 bias/mask tables, -inf pad ----------------
// thread = one (tb, i, lq, p) -> 8 contiguous f16. tb<64: mask w; else bias h.
__global__ __launch_bounds__(256) void k_bmt(const float* __restrict__ mask,
                                             const float* __restrict__ tbl,
                                             const int* __restrict__ ridx,
                                             _Float16* __restrict__ mT,
                                             _Float16* __restrict__ bT){
  int idx = blockIdx.x*256 + threadIdx.x;
  const int tot = 72*NN*4*11;
  if (idx >= tot) return;
  int p  = idx % 11;
  int r1 = idx / 11;
  int lq = r1 & 3;
  int r2 = r1 >> 2;
  int i  = r2 % NN;
  int tb = r2 / NN;
  const u16 NEGINF = 0xFC00u;
  u16 buf[8];
  _Float16* dst;
  if (tb < 64){
    const float* mrow = mask + ((size_t)tb*NN + i)*NN;
    #pragma unroll
    for (int e=0;e<8;e++){
      int jt  = 2*p + (e>>2);
      int col = jt*16 + lq*4 + (e&3);
      buf[e] = (col < NN) ? f2h(mrow[col]) : NEGINF;
    }
    dst = mT + (((size_t)tb*NN + i)*4 + lq)*88 + p*8;
  } else {
    int hh = tb - 64;
    const int* rrow = ridx + (size_t)i*NN;
    #pragma unroll
    for (int e=0;e<8;e++){
      int jt  = 2*p + (e>>2);
      int col = jt*16 + lq*4 + (e&3);
      buf[e] = (col < NN) ? f2h(tbl[rrow[col]*NH + hh]) : NEGINF;
    }
    dst = bT + (((size_t)hh*NN + i)*4 + lq)*88 + p*8;
  }
  *(uint4*)dst = *(uint4*)buf;
}

// ---------------- K1: qkv GEMM, fused x f32->f16 staging ----------------
// grid = 686*6; output layout per stream: [bh][343][32] u16 (q,k bf16 / v f16)
__global__ __launch_bounds__(256,4) void k_qkv(const float* __restrict__ x,
                                               const _Float16* __restrict__ wT,
                                               const float* __restrict__ qkvb,
                                               u16* __restrict__ qws,
                                               u16* __restrict__ kws,
                                               u16* __restrict__ vws){
  const int nt = blockIdx.x % 6;
  const int mt = blockIdx.x / 6;
  const int m0 = mt*128, n0 = nt*128;
  __shared__ _Float16 As[128*32];
  __shared__ _Float16 Bs[128*32];
  const int t = threadIdx.x;
  const int wv = t >> 6, ln = t & 63, lc = ln & 15, lq = ln >> 4;
  const int wm = wv & 1, wn = wv >> 1;
  const float*    gax = x  + (size_t)(m0 + (t>>2))*CC + (t&3)*8;
  const _Float16* gb  = wT + (size_t)(n0 + (t>>2))*CC + (t&3)*8;
  f4 acc[4][4];
  #pragma unroll
  for (int i=0;i<4;i++)
    #pragma unroll
    for (int j=0;j<4;j++) acc[i][j] = (f4){0.f,0.f,0.f,0.f};
  for (int kc=0; kc<256; kc+=32){
    float4 a0 = *(const float4*)(gax + kc);
    float4 a1 = *(const float4*)(gax + kc + 4);
    float4 b0 = *(const float4*)(gax + 64*CC + kc);
    float4 b1 = *(const float4*)(gax + 64*CC + kc + 4);
    __syncthreads();
    cp16(gb + kc,          Bs + t*8);
    cp16(gb + kc + 64*CC,  Bs + 2048 + t*8);
    ushort4 pa[2], pb_[2];
    pa[0].x=f2h(a0.x); pa[0].y=f2h(a0.y); pa[0].z=f2h(a0.z); pa[0].w=f2h(a0.w);
    pa[1].x=f2h(a1.x); pa[1].y=f2h(a1.y); pa[1].z=f2h(a1.z); pa[1].w=f2h(a1.w);
    pb_[0].x=f2h(b0.x); pb_[0].y=f2h(b0.y); pb_[0].z=f2h(b0.z); pb_[0].w=f2h(b0.w);
    pb_[1].x=f2h(b1.x); pb_[1].y=f2h(b1.y); pb_[1].z=f2h(b1.z); pb_[1].w=f2h(b1.w);
    *(uint4*)(As + t*8)        = *(uint4*)&pa[0];
    *(uint4*)(As + 2048 + t*8) = *(uint4*)&pb_[0];
    __syncthreads();
    h8 af[4], bf[4];
    #pragma unroll
    for (int mi=0;mi<4;mi++) af[mi] = *(const h8*)(As + (wm*64 + mi*16 + lc)*32 + lq*8);
    #pragma unroll
    for (int ni=0;ni<4;ni++) bf[ni] = *(const h8*)(Bs + (wn*64 + ni*16 + lc)*32 + lq*8);
    #pragma unroll
    for (int mi=0;mi<4;mi++)
      #pragma unroll
      for (int ni=0;ni<4;ni++)
        acc[mi][ni] = __builtin_amdgcn_mfma_f32_16x16x32_f16(af[mi], bf[ni], acc[mi][ni], 0,0,0);
  }
  // epilogue: stream s and head h are block/ni-uniform; [bh][i][d] layout stores
  const int s = nt >> 1;               // 0=q 1=k 2=v
  u16* dst = (s==0) ? qws : (s==1) ? kws : vws;
  float bias4[4];
  #pragma unroll
  for (int ni=0;ni<4;ni++) bias4[ni] = qkvb[n0 + wn*64 + ni*16 + lc];
  #pragma unroll
  for (int mi=0;mi<4;mi++){
    #pragma unroll
    for (int r=0;r<4;r++){
      int m = m0 + wm*64 + mi*16 + lq*4 + r;
      int b = m / NN;
      int i = m - b*NN;
      #pragma unroll
      for (int ni=0;ni<4;ni++){
        int hh = (nt&1)*4 + wn*2 + (ni>>1);   // head, uniform per (block,wave,ni)
        int d0 = (ni&1)*16;
        float val = acc[mi][ni][r] + bias4[ni];
        u16 o;
        if      (s == 0) o = f2bf(val*SCALE_);
        else if (s == 1) o = f2bf(val);
        else             o = f2h(val);
        dst[((size_t)(b*NH + hh)*NN + i)*HD + d0 + lc] = o;
      }
    }
  }
}

// ---------------- K2: MFMA flash attention, swapped-QK + XCD-clustered mT ----------------
// grid = 2048, block 256 (4 waves). LDS = 25344+23296+4608 = 53248 (3 blk/CU)
// block swizzle: all 32 blocks sharing mT[w] satisfy blockIdx%8 == w%8 -> same XCD L2
#define KSTR 36
#define VSTR 364
#define PSTR 36
__global__ __launch_bounds__(256,3) void k_attn(const u16* __restrict__ qws,
                                                const u16* __restrict__ kws,
                                                const u16* __restrict__ vws,
                                                const _Float16* __restrict__ mT,
                                                const _Float16* __restrict__ bT,
                                                u16* __restrict__ ctxh){
  __shared__ u16 Klds[352*KSTR];
  __shared__ u16 Vt[HD*VSTR];
  __shared__ u16 PchT[4][16*PSTR];
  const int B_   = blockIdx.x;
  const int xcd  = B_ & 7;
  const int rest = B_ >> 3;
  const int w_hi = rest >> 5;
  const int kk   = rest & 31;
  const int w = w_hi*8 + xcd;           // window slab: constant per XCD residue
  const int b = (kk >> 3)*64 + w;       // b & 63 == w
  const int h = kk & 7;
  const int bh = b*NH + h;
  const size_t kvbase = (size_t)bh * (NN*HD);
  const int t = threadIdx.x;
  // ---- stage K rows (bf16), zero-pad rows 343..351 ----
  for (int task = t; task < 352*4; task += 256){
    int j = task >> 2, d0 = (task & 3) << 3;
    uint4 val = {0u,0u,0u,0u};
    if (j < NN) val = *(const uint4*)(kws + kvbase + j*HD + d0);
    *(uint2*)&Klds[j*KSTR + d0]     = make_uint2(val.x, val.y);
    *(uint2*)&Klds[j*KSTR + d0 + 4] = make_uint2(val.z, val.w);
  }
  // ---- stage V transposed: Vt[d][j], zero-pad j>=343 ----
  for (int task = t; task < 88*4; task += 256){
    int jg = task >> 2, d0 = (task & 3) << 3;
    int j0 = jg*4;
    uint4 r0={0,0,0,0}, r1={0,0,0,0}, r2={0,0,0,0}, r3={0,0,0,0};
    const u16* vsrc = vws + kvbase;
    if (j0   < NN) r0 = *(const uint4*)(vsrc + (size_t)(j0  )*HD + d0);
    if (j0+1 < NN) r1 = *(const uint4*)(vsrc + (size_t)(j0+1)*HD + d0);
    if (j0+2 < NN) r2 = *(const uint4*)(vsrc + (size_t)(j0+2)*HD + d0);
    if (j0+3 < NN) r3 = *(const uint4*)(vsrc + (size_t)(j0+3)*HD + d0);
    const u32* p0=(const u32*)&r0; const u32* p1=(const u32*)&r1;
    const u32* p2=(const u32*)&r2; const u32* p3=(const u32*)&r3;
    #pragma unroll
    for (int e=0;e<8;e++){
      int sh_ = (e&1)*16;
      ushort4 c4;
      c4.x = (u16)(p0[e>>1] >> sh_);
      c4.y = (u16)(p1[e>>1] >> sh_);
      c4.z = (u16)(p2[e>>1] >> sh_);
      c4.w = (u16)(p3[e>>1] >> sh_);
      *(ushort4*)&Vt[(d0+e)*VSTR + j0] = c4;
    }
  }
  __syncthreads();
  const int wv = t >> 6, ln = t & 63;
  const int lc = ln & 15, lq = ln >> 4;
  u16* pch = &PchT[wv][0];
  const f4 z4 = {0.f,0.f,0.f,0.f};
  for (int sub = wv; sub < 22; sub += 4){
    int qrow = sub*16 + lc; if (qrow > NN-1) qrow = NN-1;
    // B-frag: Q row i = lc-indexed
    s8v qa = *(const s8v*)(qws + kvbase + (size_t)qrow*HD + lq*8);
    // lane-contiguous table rows: 11 h8 chunks each (chunk p covers jt=2p,2p+1)
    const _Float16* mrow = mT + (((size_t)w*NN + qrow)*4 + lq)*88;
    const _Float16* brow = bT + (((size_t)h*NN + qrow)*4 + lq)*88;
    h8 sh6[6];
    #pragma unroll
    for (int p=0;p<6;p++)
      sh6[p] = *(const h8*)(mrow + p*8) + *(const h8*)(brow + p*8);
    // QK^T swapped: D[j][i], j = jt*16+lq*4+r, i = sub*16+lc
    f4 acc[22];
    #pragma unroll
    for (int jt=0; jt<22; jt++){
      const u16* kp = &Klds[(jt*16+lc)*KSTR + lq*8];
      s4v k0 = *(const s4v*)kp;
      s4v k1 = *(const s4v*)(kp+4);
      s8v bk = {k0[0],k0[1],k0[2],k0[3],k1[0],k1[1],k1[2],k1[3]};
      acc[jt] = __builtin_amdgcn_mfma_f32_16x16x32_bf16(bk, qa, z4, 0,0,0);
    }
    // bias+mask add + running max (per i = lc; in-lane over j)
    float mx0=-INFINITY, mx1=-INFINITY, mx2=-INFINITY, mx3=-INFINITY;
    #pragma unroll
    for (int p=0; p<11; p++){
      h8 s8 = (p < 6) ? sh6[p]
            : (*(const h8*)(mrow + p*8) + *(const h8*)(brow + p*8));
      f4 a = acc[2*p], c = acc[2*p+1];
      a[0] += (float)s8[0]; a[1] += (float)s8[1];
      a[2] += (float)s8[2]; a[3] += (float)s8[3];
      c[0] += (float)s8[4]; c[1] += (float)s8[5];
      c[2] += (float)s8[6]; c[3] += (float)s8[7];
      acc[2*p] = a; acc[2*p+1] = c;
      mx0 = fmaxf(mx0, fmaxf(a[0], c[0]));
      mx1 = fmaxf(mx1, fmaxf(a[1], c[1]));
      mx2 = fmaxf(mx2, fmaxf(a[2], c[2]));
      mx3 = fmaxf(mx3, fmaxf(a[3], c[3]));
    }
    float mx = fmaxf(fmaxf(mx0,mx1), fmaxf(mx2,mx3));
    mx = fmaxf(mx, __shfl_xor(mx, 16));
    mx = fmaxf(mx, __shfl_xor(mx, 32));
    float mxl = mx * LOG2E_;
    // exp + sum
    f4 ps = z4;
    #pragma unroll
    for (int jt=0; jt<22; jt++){
      f4 a = acc[jt];
      a[0] = exp2f(__builtin_fmaf(a[0], LOG2E_, -mxl));
      a[1] = exp2f(__builtin_fmaf(a[1], LOG2E_, -mxl));
      a[2] = exp2f(__builtin_fmaf(a[2], LOG2E_, -mxl));
      a[3] = exp2f(__builtin_fmaf(a[3], LOG2E_, -mxl));
      acc[jt] = a;
      ps += a;
    }
    float l = (ps[0]+ps[1]) + (ps[2]+ps[3]);
    l += __shfl_xor(l, 16);
    l += __shfl_xor(l, 32);
    float inv = __builtin_amdgcn_rcpf(l);
    // PV: O^T[d][i] += V^T[d][j] * P^T[j][i]
    f4 o0 = z4, o1 = z4;
    #pragma unroll
    for (int kt=0; kt<11; kt++){
      int ja = kt*2, jb = kt*2+1;
      u32 w0 = __builtin_bit_cast(u32, __builtin_amdgcn_cvt_pkrtz(acc[ja][0], acc[ja][1]));
      u32 w1 = __builtin_bit_cast(u32, __builtin_amdgcn_cvt_pkrtz(acc[ja][2], acc[ja][3]));
      u32 w2 = __builtin_bit_cast(u32, __builtin_amdgcn_cvt_pkrtz(acc[jb][0], acc[jb][1]));
      u32 w3 = __builtin_bit_cast(u32, __builtin_amdgcn_cvt_pkrtz(acc[jb][2], acc[jb][3]));
      *(uint2*)(pch + lc*PSTR + lq*4)      = make_uint2(w0, w1);
      *(uint2*)(pch + lc*PSTR + 16 + lq*4) = make_uint2(w2, w3);
      h8 pb = *(const h8*)((const _Float16*)pch + lc*PSTR + lq*8);
      h8 va0 = *(const h8*)((const _Float16*)&Vt[(lc   )*VSTR + kt*32 + lq*8]);
      h8 va1 = *(const h8*)((const _Float16*)&Vt[(lc+16)*VSTR + kt*32 + lq*8]);
      o0 = __builtin_amdgcn_mfma_f32_16x16x32_f16(va0, pb, o0, 0,0,0);
      o1 = __builtin_amdgcn_mfma_f32_16x16x32_f16(va1, pb, o1, 0,0,0);
    }
    // write: lane owns row i=lc, d = lq*4+r (+16)
    int i = sub*16 + lc;
    if (i < NN){
      u16* op = ctxh + ((size_t)(b*NN + i))*CC + h*HD;
      u32 q0 = (u32)f2h(o0[0]*inv) | ((u32)f2h(o0[1]*inv) << 16);
      u32 q1 = (u32)f2h(o0[2]*inv) | ((u32)f2h(o0[3]*inv) << 16);
      u32 q2 = (u32)f2h(o1[0]*inv) | ((u32)f2h(o1[1]*inv) << 16);
      u32 q3 = (u32)f2h(o1[2]*inv) | ((u32)f2h(o1[3]*inv) << 16);
      *(uint2*)(op + lq*4)      = make_uint2(q0, q1);
      *(uint2*)(op + 16 + lq*4) = make_uint2(q2, q3);
    }
  }
}

// ---------------- K3: proj GEMM via fp16 MFMA ----------------
__global__ __launch_bounds__(256,4) void k_proj(const _Float16* __restrict__ ctxh,
                                                const _Float16* __restrict__ pwT,
                                                const float* __restrict__ pb,
                                                float* __restrict__ out){
  const int nt = blockIdx.x & 1;
  const int mt = blockIdx.x >> 1;
  const int m0 = mt*128, n0 = nt*128;
  __shared__ _Float16 As[128*32];
  __shared__ _Float16 Bs[128*32];
  const int t = threadIdx.x;
  const int wv = t >> 6, ln = t & 63, lc = ln & 15, lq = ln >> 4;
  const int wm = wv & 1, wn = wv >> 1;
  const _Float16* ga = ctxh + (size_t)(m0 + (t>>2))*CC + (t&3)*8;
  const _Float16* gb = pwT  + (size_t)(n0 + (t>>2))*CC + (t&3)*8;
  f4 acc[4][4];
  #pragma unroll
  for (int i=0;i<4;i++)
    #pragma unroll
    for (int j=0;j<4;j++) acc[i][j] = (f4){0.f,0.f,0.f,0.f};
  for (int kc=0; kc<256; kc+=32){
    __syncthreads();
    cp16(ga + kc,          As + t*8);
    cp16(ga + kc + 64*CC,  As + 2048 + t*8);
    cp16(gb + kc,          Bs + t*8);
    cp16(gb + kc + 64*CC,  Bs + 2048 + t*8);
    __syncthreads();
    h8 af[4], bf[4];
    #pragma unroll
    for (int mi=0;mi<4;mi++) af[mi] = *(const h8*)(As + (wm*64 + mi*16 + lc)*32 + lq*8);
    #pragma unroll
    for (int ni=0;ni<4;ni++) bf[ni] = *(const h8*)(Bs + (wn*64 + ni*16 + lc)*32 + lq*8);
    #pragma unroll
    for (int mi=0;mi<4;mi++)
      #pragma unroll
      for (int ni=0;ni<4;ni++)
        acc[mi][ni] = __builtin_amdgcn_mfma_f32_16x16x32_f16(af[mi], bf[ni], acc[mi][ni], 0,0,0);
  }
  float bias4[4];
  #pragma unroll
  for (int ni=0;ni<4;ni++) bias4[ni] = pb[n0 + wn*64 + ni*16 + lc];
  #pragma unroll
  for (int mi=0;mi<4;mi++){
    #pragma unroll
    for (int r=0;r<4;r++){
      int m = m0 + wm*64 + mi*16 + lq*4 + r;
      float* orow = out + (size_t)m*CC + n0 + wn*64;
      #pragma unroll
      for (int ni=0;ni<4;ni++)
        orow[ni*16 + lc] = acc[mi][ni][r] + bias4[ni];
    }
  }
}

extern "C" void kernel_launch(void* const* d_in, const int* in_sizes, int n_in,
                              void* d_out, int out_size, void* d_ws, size_t ws_size,
                              hipStream_t stream){
  (void)in_sizes; (void)n_in; (void)out_size; (void)ws_size;
  const float* x   = (const float*)d_in[0];
  const float* msk = (const float*)d_in[1];
  const float* qw  = (const float*)d_in[2];
  const float* qb  = (const float*)d_in[3];
  const float* pw  = (const float*)d_in[4];
  const float* pb  = (const float*)d_in[5];
  const float* tbl = (const float*)d_in[6];
  const int*   rix = (const int*)d_in[7];
  float* out = (float*)d_out;
  char* ws = (char*)d_ws;
  u16*      qws    = (u16*)(ws + OFF_Q);
  u16*      kws    = (u16*)(ws + OFF_K);
  u16*      vws    = (u16*)(ws + OFF_V);
  _Float16* ctxh   = (_Float16*)(ws + OFF_CTXH);
  _Float16* wT     = (_Float16*)(ws + OFF_WT);
  _Float16* pwT    = (_Float16*)(ws + OFF_PWT);
  _Float16* mT     = (_Float16*)(ws + OFF_MT);
  _Float16* bT     = (_Float16*)(ws + OFF_BT);

  hipLaunchKernelGGL(k_cvt_w, dim3(128), dim3(256), 0, stream, qw, pw, wT, pwT);
  hipLaunchKernelGGL(k_bmt,   dim3((72*NN*4*11 + 255)/256), dim3(256), 0, stream, msk, tbl, rix, mT, bT);
  hipLaunchKernelGGL(k_qkv,   dim3(686*6), dim3(256), 0, stream, x, wT, qb, qws, kws, vws);
  hipLaunchKernelGGL(k_attn,  dim3(NB*NH), dim3(256), 0, stream, qws, kws, vws, mT, bT, (u16*)ctxh);
  hipLaunchKernelGGL(k_proj,  dim3(686*2), dim3(256), 0, stream, ctxh, pwT, pb, out);
}

// Round 6
// 650.241 us; speedup vs baseline: 1.1653x; 1.0402x over previous
//
#include <hip/hip_runtime.h>
#include <stdint.h>

#define NB   256
#define NN   343
#define CC   256
#define NH   8
#define HD   32
#define NWIN 64
#define SCALE_ 0.17677669529663689f
#define LOG2E_ 1.4426950408889634f

typedef unsigned int u32;
typedef unsigned short u16;
typedef float f4 __attribute__((ext_vector_type(4)));
typedef short s8v __attribute__((ext_vector_type(8)));
typedef short s4v __attribute__((ext_vector_type(4)));
typedef _Float16 h8 __attribute__((ext_vector_type(8)));
typedef _Float16 h4 __attribute__((ext_vector_type(4)));

// ws layout (bytes); total 229,077,536 (unchanged footprint)
#define OFF_Q    0ull
#define OFF_K    44957696ull           // 87808*256*2
#define OFF_V    89915392ull
#define OFF_XH   134873088ull          // bias/mask tables live here
#define OFF_CTXH 179830784ull          // ctx as fp16, 45 MB
#define OFF_WT   228553248ull          // qkv_w^T fp16 [768][256]
#define OFF_PWT  228946464ull          // proj_w^T fp16 [256][256]

// tables, lane-contiguous layout: tab[slab][i][lq][p][e] f16 where
// logical col = (2p + (e>>2))*16 + lq*4 + (e&3), p=0..10, e=0..7 (88 per lq)
#define OFF_MT   OFF_XH
#define OFF_BT   (OFF_XH + 15454208ull)

__device__ __forceinline__ u16 f2bf(float f){
  u32 u = __float_as_uint(f);
  u = u + 0x7fffu + ((u >> 16) & 1u);   // RNE
  return (u16)(u >> 16);
}
__device__ __forceinline__ u16 f2h(float f){
  _Float16 h = (_Float16)f;
  return __builtin_bit_cast(u16, h);
}
__device__ __forceinline__ void cp16(const void* g, void* s){
  __builtin_amdgcn_global_load_lds(
    (const __attribute__((address_space(1))) unsigned int*)g,
    (__attribute__((address_space(3))) unsigned int*)s, 16, 0, 0);
}

// ---------------- K0c: transpose+convert weights ----------------
__global__ __launch_bounds__(256) void k_cvt_w(const float* __restrict__ qw,
                                               const float* __restrict__ pw,
                                               _Float16* __restrict__ wT,
                                               _Float16* __restrict__ pwT){
  int idx = blockIdx.x*256 + threadIdx.x;
  int row = idx >> 5;
  int k0  = (idx & 31) << 3;
  const float* src; int stride; _Float16* dst;
  if (row < 768){ src = qw + row;        stride = 768; dst = wT  + (size_t)row*256 + k0; }
  else          { src = pw + (row-768);  stride = 256; dst = pwT + (size_t)(row-768)*256 + k0; }
  ushort4 pk[2];
  u16* p = (u16*)&pk[0];
  #pragma unroll
  for (int j=0;j<8;j++) p[j] = f2h(src[(size_t)(k0+j)*stride]);
  *(uint4*)dst = *(uint4*)&pk[0];
}

// ---------------- K0d: lane-contiguous f16 bias/mask tables, -inf pad ----------------
__global__ __launch_bounds__(256) void k_bmt(const float* __restrict__ mask,
                                             const float* __restrict__ tbl,
                                             const int* __restrict__ ridx,
                                             _Float16* __restrict__ mT,
                                             _Float16* __restrict__ bT){
  int idx = blockIdx.x*256 + threadIdx.x;
  const int tot = 72*NN*4*11;
  if (idx >= tot) return;
  int p  = idx % 11;
  int r1 = idx / 11;
  int lq = r1 & 3;
  int r2 = r1 >> 2;
  int i  = r2 % NN;
  int tb = r2 / NN;
  const u16 NEGINF = 0xFC00u;
  u16 buf[8];
  _Float16* dst;
  if (tb < 64){
    const float* mrow = mask + ((size_t)tb*NN + i)*NN;
    #pragma unroll
    for (int e=0;e<8;e++){
      int jt  = 2*p + (e>>2);
      int col = jt*16 + lq*4 + (e&3);
      buf[e] = (col < NN) ? f2h(mrow[col]) : NEGINF;
    }
    dst = mT + (((size_t)tb*NN + i)*4 + lq)*88 + p*8;
  } else {
    int hh = tb - 64;
    const int* rrow = ridx + (size_t)i*NN;
    #pragma unroll
    for (int e=0;e<8;e++){
      int jt  = 2*p + (e>>2);
      int col = jt*16 + lq*4 + (e&3);
      buf[e] = (col < NN) ? f2h(tbl[rrow[col]*NH + hh]) : NEGINF;
    }
    dst = bT + (((size_t)hh*NN + i)*4 + lq)*88 + p*8;
  }
  *(uint4*)dst = *(uint4*)buf;
}

// ---------------- K1: qkv GEMM, fused x f32->f16 staging ----------------
// grid = 686*6; output layout per stream: [bh][343][32] u16 (q,k bf16 / v f16)
__global__ __launch_bounds__(256,4) void k_qkv(const float* __restrict__ x,
                                               const _Float16* __restrict__ wT,
                                               const float* __restrict__ qkvb,
                                               u16* __restrict__ qws,
                                               u16* __restrict__ kws,
                                               u16* __restrict__ vws){
  const int nt = blockIdx.x % 6;
  const int mt = blockIdx.x / 6;
  const int m0 = mt*128, n0 = nt*128;
  __shared__ _Float16 As[128*32];
  __shared__ _Float16 Bs[128*32];
  const int t = threadIdx.x;
  const int wv = t >> 6, ln = t & 63, lc = ln & 15, lq = ln >> 4;
  const int wm = wv & 1, wn = wv >> 1;
  const float*    gax = x  + (size_t)(m0 + (t>>2))*CC + (t&3)*8;
  const _Float16* gb  = wT + (size_t)(n0 + (t>>2))*CC + (t&3)*8;
  f4 acc[4][4];
  #pragma unroll
  for (int i=0;i<4;i++)
    #pragma unroll
    for (int j=0;j<4;j++) acc[i][j] = (f4){0.f,0.f,0.f,0.f};
  for (int kc=0; kc<256; kc+=32){
    float4 a0 = *(const float4*)(gax + kc);
    float4 a1 = *(const float4*)(gax + kc + 4);
    float4 b0 = *(const float4*)(gax + 64*CC + kc);
    float4 b1 = *(const float4*)(gax + 64*CC + kc + 4);
    __syncthreads();
    cp16(gb + kc,          Bs + t*8);
    cp16(gb + kc + 64*CC,  Bs + 2048 + t*8);
    ushort4 pa[2], pb_[2];
    pa[0].x=f2h(a0.x); pa[0].y=f2h(a0.y); pa[0].z=f2h(a0.z); pa[0].w=f2h(a0.w);
    pa[1].x=f2h(a1.x); pa[1].y=f2h(a1.y); pa[1].z=f2h(a1.z); pa[1].w=f2h(a1.w);
    pb_[0].x=f2h(b0.x); pb_[0].y=f2h(b0.y); pb_[0].z=f2h(b0.z); pb_[0].w=f2h(b0.w);
    pb_[1].x=f2h(b1.x); pb_[1].y=f2h(b1.y); pb_[1].z=f2h(b1.z); pb_[1].w=f2h(b1.w);
    *(uint4*)(As + t*8)        = *(uint4*)&pa[0];
    *(uint4*)(As + 2048 + t*8) = *(uint4*)&pb_[0];
    __syncthreads();
    h8 af[4], bf[4];
    #pragma unroll
    for (int mi=0;mi<4;mi++) af[mi] = *(const h8*)(As + (wm*64 + mi*16 + lc)*32 + lq*8);
    #pragma unroll
    for (int ni=0;ni<4;ni++) bf[ni] = *(const h8*)(Bs + (wn*64 + ni*16 + lc)*32 + lq*8);
    #pragma unroll
    for (int mi=0;mi<4;mi++)
      #pragma unroll
      for (int ni=0;ni<4;ni++)
        acc[mi][ni] = __builtin_amdgcn_mfma_f32_16x16x32_f16(af[mi], bf[ni], acc[mi][ni], 0,0,0);
  }
  // epilogue: stream s and head h are block/ni-uniform; [bh][i][d] layout stores
  const int s = nt >> 1;               // 0=q 1=k 2=v
  u16* dst = (s==0) ? qws : (s==1) ? kws : vws;
  float bias4[4];
  #pragma unroll
  for (int ni=0;ni<4;ni++) bias4[ni] = qkvb[n0 + wn*64 + ni*16 + lc];
  #pragma unroll
  for (int mi=0;mi<4;mi++){
    #pragma unroll
    for (int r=0;r<4;r++){
      int m = m0 + wm*64 + mi*16 + lq*4 + r;
      int b = m / NN;
      int i = m - b*NN;
      #pragma unroll
      for (int ni=0;ni<4;ni++){
        int hh = (nt&1)*4 + wn*2 + (ni>>1);   // head, uniform per (block,wave,ni)
        int d0 = (ni&1)*16;
        float val = acc[mi][ni][r] + bias4[ni];
        u16 o;
        if      (s == 0) o = f2bf(val*SCALE_);
        else if (s == 1) o = f2bf(val);
        else             o = f2h(val);
        dst[((size_t)(b*NH + hh)*NN + i)*HD + d0 + lc] = o;
      }
    }
  }
}

// ---------------- K2: MFMA flash attention, swapped-QK + XCD-clustered mT ----------------
// grid = 2048, block 256 (4 waves). LDS = 25344+23296+4608 = 53248 (3 blk/CU)
// block swizzle: all 32 blocks sharing mT[w] satisfy blockIdx%8 == w%8 -> same XCD L2
#define KSTR 36
#define VSTR 364
#define PSTR 36
__global__ __launch_bounds__(256,3) void k_attn(const u16* __restrict__ qws,
                                                const u16* __restrict__ kws,
                                                const u16* __restrict__ vws,
                                                const _Float16* __restrict__ mT,
                                                const _Float16* __restrict__ bT,
                                                u16* __restrict__ ctxh){
  __shared__ u16 Klds[352*KSTR];
  __shared__ u16 Vt[HD*VSTR];
  __shared__ u16 PchT[4][16*PSTR];
  const int B_   = blockIdx.x;
  const int xcd  = B_ & 7;
  const int rest = B_ >> 3;
  const int w_hi = rest >> 5;
  const int kk   = rest & 31;
  const int w = w_hi*8 + xcd;           // window slab: constant per XCD residue
  const int b = (kk >> 3)*64 + w;       // b & 63 == w
  const int h = kk & 7;
  const int bh = b*NH + h;
  const size_t kvbase = (size_t)bh * (NN*HD);
  const int t = threadIdx.x;
  // ---- stage K rows (bf16), zero-pad rows 343..351 ----
  for (int task = t; task < 352*4; task += 256){
    int j = task >> 2, d0 = (task & 3) << 3;
    uint4 val = {0u,0u,0u,0u};
    if (j < NN) val = *(const uint4*)(kws + kvbase + j*HD + d0);
    *(uint2*)&Klds[j*KSTR + d0]     = make_uint2(val.x, val.y);
    *(uint2*)&Klds[j*KSTR + d0 + 4] = make_uint2(val.z, val.w);
  }
  // ---- stage V transposed: Vt[d][j], zero-pad j>=343 ----
  for (int task = t; task < 88*4; task += 256){
    int jg = task >> 2, d0 = (task & 3) << 3;
    int j0 = jg*4;
    uint4 r0={0,0,0,0}, r1={0,0,0,0}, r2={0,0,0,0}, r3={0,0,0,0};
    const u16* vsrc = vws + kvbase;
    if (j0   < NN) r0 = *(const uint4*)(vsrc + (size_t)(j0  )*HD + d0);
    if (j0+1 < NN) r1 = *(const uint4*)(vsrc + (size_t)(j0+1)*HD + d0);
    if (j0+2 < NN) r2 = *(const uint4*)(vsrc + (size_t)(j0+2)*HD + d0);
    if (j0+3 < NN) r3 = *(const uint4*)(vsrc + (size_t)(j0+3)*HD + d0);
    const u32* p0=(const u32*)&r0; const u32* p1=(const u32*)&r1;
    const u32* p2=(const u32*)&r2; const u32* p3=(const u32*)&r3;
    #pragma unroll
    for (int e=0;e<8;e++){
      int sh_ = (e&1)*16;
      ushort4 c4;
      c4.x = (u16)(p0[e>>1] >> sh_);
      c4.y = (u16)(p1[e>>1] >> sh_);
      c4.z = (u16)(p2[e>>1] >> sh_);
      c4.w = (u16)(p3[e>>1] >> sh_);
      *(ushort4*)&Vt[(d0+e)*VSTR + j0] = c4;
    }
  }
  __syncthreads();
  const int wv = t >> 6, ln = t & 63;
  const int lc = ln & 15, lq = ln >> 4;
  u16* pch = &PchT[wv][0];
  const f4 z4 = {0.f,0.f,0.f,0.f};
  for (int sub = wv; sub < 22; sub += 4){
    int qrow = sub*16 + lc; if (qrow > NN-1) qrow = NN-1;
    // B-frag: Q row i = lc-indexed
    s8v qa = *(const s8v*)(qws + kvbase + (size_t)qrow*HD + lq*8);
    // lane-contiguous table rows: 11 h8 chunks each (chunk p covers jt=2p,2p+1)
    const _Float16* mrow = mT + (((size_t)w*NN + qrow)*4 + lq)*88;
    const _Float16* brow = bT + (((size_t)h*NN + qrow)*4 + lq)*88;
    h8 sh6[6];
    #pragma unroll
    for (int p=0;p<6;p++)
      sh6[p] = *(const h8*)(mrow + p*8) + *(const h8*)(brow + p*8);
    // QK^T swapped: D[j][i], j = jt*16+lq*4+r, i = sub*16+lc
    f4 acc[22];
    #pragma unroll
    for (int jt=0; jt<22; jt++){
      const u16* kp = &Klds[(jt*16+lc)*KSTR + lq*8];
      s4v k0 = *(const s4v*)kp;
      s4v k1 = *(const s4v*)(kp+4);
      s8v bk = {k0[0],k0[1],k0[2],k0[3],k1[0],k1[1],k1[2],k1[3]};
      acc[jt] = __builtin_amdgcn_mfma_f32_16x16x32_bf16(bk, qa, z4, 0,0,0);
    }
    // bias+mask add + running max (per i = lc; in-lane over j)
    float mx0=-INFINITY, mx1=-INFINITY, mx2=-INFINITY, mx3=-INFINITY;
    #pragma unroll
    for (int p=0; p<11; p++){
      h8 s8 = (p < 6) ? sh6[p]
            : (*(const h8*)(mrow + p*8) + *(const h8*)(brow + p*8));
      f4 a = acc[2*p], c = acc[2*p+1];
      a[0] += (float)s8[0]; a[1] += (float)s8[1];
      a[2] += (float)s8[2]; a[3] += (float)s8[3];
      c[0] += (float)s8[4]; c[1] += (float)s8[5];
      c[2] += (float)s8[6]; c[3] += (float)s8[7];
      acc[2*p] = a; acc[2*p+1] = c;
      mx0 = fmaxf(mx0, fmaxf(a[0], c[0]));
      mx1 = fmaxf(mx1, fmaxf(a[1], c[1]));
      mx2 = fmaxf(mx2, fmaxf(a[2], c[2]));
      mx3 = fmaxf(mx3, fmaxf(a[3], c[3]));
    }
    float mx = fmaxf(fmaxf(mx0,mx1), fmaxf(mx2,mx3));
    mx = fmaxf(mx, __shfl_xor(mx, 16));
    mx = fmaxf(mx, __shfl_xor(mx, 32));
    float mxl = mx * LOG2E_;
    // exp + sum
    f4 ps = z4;
    #pragma unroll
    for (int jt=0; jt<22; jt++){
      f4 a = acc[jt];
      a[0] = exp2f(__builtin_fmaf(a[0], LOG2E_, -mxl));
      a[1] = exp2f(__builtin_fmaf(a[1], LOG2E_, -mxl));
      a[2] = exp2f(__builtin_fmaf(a[2], LOG2E_, -mxl));
      a[3] = exp2f(__builtin_fmaf(a[3], LOG2E_, -mxl));
      acc[jt] = a;
      ps += a;
    }
    float l = (ps[0]+ps[1]) + (ps[2]+ps[3]);
    l += __shfl_xor(l, 16);
    l += __shfl_xor(l, 32);
    float inv = __builtin_amdgcn_rcpf(l);
    // PV: O^T[d][i] += V^T[d][j] * P^T[j][i]
    f4 o0 = z4, o1 = z4;
    #pragma unroll
    for (int kt=0; kt<11; kt++){
      int ja = kt*2, jb = kt*2+1;
      u32 w0 = __builtin_bit_cast(u32, __builtin_amdgcn_cvt_pkrtz(acc[ja][0], acc[ja][1]));
      u32 w1 = __builtin_bit_cast(u32, __builtin_amdgcn_cvt_pkrtz(acc[ja][2], acc[ja][3]));
      u32 w2 = __builtin_bit_cast(u32, __builtin_amdgcn_cvt_pkrtz(acc[jb][0], acc[jb][1]));
      u32 w3 = __builtin_bit_cast(u32, __builtin_amdgcn_cvt_pkrtz(acc[jb][2], acc[jb][3]));
      *(uint2*)(pch + lc*PSTR + lq*4)      = make_uint2(w0, w1);
      *(uint2*)(pch + lc*PSTR + 16 + lq*4) = make_uint2(w2, w3);
      h8 pb = *(const h8*)((const _Float16*)pch + lc*PSTR + lq*8);
      h8 va0 = *(const h8*)((const _Float16*)&Vt[(lc   )*VSTR + kt*32 + lq*8]);
      h8 va1 = *(const h8*)((const _Float16*)&Vt[(lc+16)*VSTR + kt*32 + lq*8]);
      o0 = __builtin_amdgcn_mfma_f32_16x16x32_f16(va0, pb, o0, 0,0,0);
      o1 = __builtin_amdgcn_mfma_f32_16x16x32_f16(va1, pb, o1, 0,0,0);
    }
    // ---- O transpose through LDS so consecutive lanes store contiguous bytes ----
    // write (same conflict-free pattern as P staging): lane holds row lc, d=lq*4+e
    u32 q0 = (u32)f2h(o0[0]*inv) | ((u32)f2h(o0[1]*inv) << 16);
    u32 q1 = (u32)f2h(o0[2]*inv) | ((u32)f2h(o0[3]*inv) << 16);
    u32 q2 = (u32)f2h(o1[0]*inv) | ((u32)f2h(o1[1]*inv) << 16);
    u32 q3 = (u32)f2h(o1[2]*inv) | ((u32)f2h(o1[3]*inv) << 16);
    *(uint2*)(pch + lc*PSTR + lq*4)      = make_uint2(q0, q1);
    *(uint2*)(pch + lc*PSTR + 16 + lq*4) = make_uint2(q2, q3);
    // read back: lane (lc,lq) covers row e*4+lq, d = lc*2..lc*2+1 -> 64-B runs
    #pragma unroll
    for (int e=0;e<4;e++){
      int i = sub*16 + e*4 + lq;
      u32 val = *(const u32*)(pch + (e*4+lq)*PSTR + lc*2);
      if (i < NN)
        *(u32*)(ctxh + ((size_t)(b*NN + i))*CC + h*HD + lc*2) = val;
    }
  }
}

// ---------------- K3: proj GEMM via fp16 MFMA ----------------
__global__ __launch_bounds__(256,4) void k_proj(const _Float16* __restrict__ ctxh,
                                                const _Float16* __restrict__ pwT,
                                                const float* __restrict__ pb,
                                                float* __restrict__ out){
  const int nt = blockIdx.x & 1;
  const int mt = blockIdx.x >> 1;
  const int m0 = mt*128, n0 = nt*128;
  __shared__ _Float16 As[128*32];
  __shared__ _Float16 Bs[128*32];
  const int t = threadIdx.x;
  const int wv = t >> 6, ln = t & 63, lc = ln & 15, lq = ln >> 4;
  const int wm = wv & 1, wn = wv >> 1;
  const _Float16* ga = ctxh + (size_t)(m0 + (t>>2))*CC + (t&3)*8;
  const _Float16* gb = pwT  + (size_t)(n0 + (t>>2))*CC + (t&3)*8;
  f4 acc[4][4];
  #pragma unroll
  for (int i=0;i<4;i++)
    #pragma unroll
    for (int j=0;j<4;j++) acc[i][j] = (f4){0.f,0.f,0.f,0.f};
  for (int kc=0; kc<256; kc+=32){
    __syncthreads();
    cp16(ga + kc,          As + t*8);
    cp16(ga + kc + 64*CC,  As + 2048 + t*8);
    cp16(gb + kc,          Bs + t*8);
    cp16(gb + kc + 64*CC,  Bs + 2048 + t*8);
    __syncthreads();
    h8 af[4], bf[4];
    #pragma unroll
    for (int mi=0;mi<4;mi++) af[mi] = *(const h8*)(As + (wm*64 + mi*16 + lc)*32 + lq*8);
    #pragma unroll
    for (int ni=0;ni<4;ni++) bf[ni] = *(const h8*)(Bs + (wn*64 + ni*16 + lc)*32 + lq*8);
    #pragma unroll
    for (int mi=0;mi<4;mi++)
      #pragma unroll
      for (int ni=0;ni<4;ni++)
        acc[mi][ni] = __builtin_amdgcn_mfma_f32_16x16x32_f16(af[mi], bf[ni], acc[mi][ni], 0,0,0);
  }
  float bias4[4];
  #pragma unroll
  for (int ni=0;ni<4;ni++) bias4[ni] = pb[n0 + wn*64 + ni*16 + lc];
  #pragma unroll
  for (int mi=0;mi<4;mi++){
    #pragma unroll
    for (int r=0;r<4;r++){
      int m = m0 + wm*64 + mi*16 + lq*4 + r;
      float* orow = out + (size_t)m*CC + n0 + wn*64;
      #pragma unroll
      for (int ni=0;ni<4;ni++)
        orow[ni*16 + lc] = acc[mi][ni][r] + bias4[ni];
    }
  }
}

extern "C" void kernel_launch(void* const* d_in, const int* in_sizes, int n_in,
                              void* d_out, int out_size, void* d_ws, size_t ws_size,
                              hipStream_t stream){
  (void)in_sizes; (void)n_in; (void)out_size; (void)ws_size;
  const float* x   = (const float*)d_in[0];
  const float* msk = (const float*)d_in[1];
  const float* qw  = (const float*)d_in[2];
  const float* qb  = (const float*)d_in[3];
  const float* pw  = (const float*)d_in[4];
  const float* pb  = (const float*)d_in[5];
  const float* tbl = (const float*)d_in[6];
  const int*   rix = (const int*)d_in[7];
  float* out = (float*)d_out;
  char* ws = (char*)d_ws;
  u16*      qws    = (u16*)(ws + OFF_Q);
  u16*      kws    = (u16*)(ws + OFF_K);
  u16*      vws    = (u16*)(ws + OFF_V);
  _Float16* ctxh   = (_Float16*)(ws + OFF_CTXH);
  _Float16* wT     = (_Float16*)(ws + OFF_WT);
  _Float16* pwT    = (_Float16*)(ws + OFF_PWT);
  _Float16* mT     = (_Float16*)(ws + OFF_MT);
  _Float16* bT     = (_Float16*)(ws + OFF_BT);

  hipLaunchKernelGGL(k_cvt_w, dim3(128), dim3(256), 0, stream, qw, pw, wT, pwT);
  hipLaunchKernelGGL(k_bmt,   dim3((72*NN*4*11 + 255)/256), dim3(256), 0, stream, msk, tbl, rix, mT, bT);
  hipLaunchKernelGGL(k_qkv,   dim3(686*6), dim3(256), 0, stream, x, wT, qb, qws, kws, vws);
  hipLaunchKernelGGL(k_attn,  dim3(NB*NH), dim3(256), 0, stream, qws, kws, vws, mT, bT, (u16*)ctxh);
  hipLaunchKernelGGL(k_proj,  dim3(686*2), dim3(256), 0, stream, ctxh, pwT, pb, out);
}

// Round 7
// 487.456 us; speedup vs baseline: 1.5544x; 1.3339x over previous
//
#include <hip/hip_runtime.h>
#include <stdint.h>

#define NB   256
#define NN   343
#define CC   256
#define NH   8
#define HD   32
#define NWIN 64
#define MM   (NB*NN)          // 87808
#define SCALE_ 0.17677669529663689f
#define LOG2E_ 1.4426950408889634f

typedef unsigned int u32;
typedef unsigned short u16;
typedef float f4 __attribute__((ext_vector_type(4)));
typedef short s8v __attribute__((ext_vector_type(8)));
typedef short s4v __attribute__((ext_vector_type(4)));
typedef _Float16 h8 __attribute__((ext_vector_type(8)));
typedef _Float16 h4 __attribute__((ext_vector_type(4)));

// ws layout (bytes); total 229,077,536
#define OFF_Q    0ull
#define OFF_K    44957696ull           // 87808*256*2
#define OFF_V    89915392ull
#define OFF_XH   134873088ull          // x as fp16, 45 MB (reused for bm tables after k_qkv)
#define OFF_CTXH 179830784ull          // ctx as fp16, 45 MB
#define OFF_BIAS 224788480ull          // (unused now)
#define OFF_WT   228553248ull          // qkv_w^T fp16 [768][256]
#define OFF_PWT  228946464ull          // proj_w^T fp16 [256][256]

// bm tables live in the xh region (dead after k_qkv):
// m16[w][i][lc][24] f16 : 64*343*16*24*2 = 16,859,136 B
// b16[h][i][lc][24] f16 :  8*343*16*24*2 =  2,107,392 B   (total 18.97 MB <= 44.96 MB)
#define OFF_M16  OFF_XH
#define OFF_B16  (OFF_XH + 16859136ull)
#define BMROW 24

__device__ __forceinline__ u16 f2bf(float f){
  u32 u = __float_as_uint(f);
  u = u + 0x7fffu + ((u >> 16) & 1u);   // RNE
  return (u16)(u >> 16);
}
__device__ __forceinline__ u16 f2h(float f){
  _Float16 h = (_Float16)f;
  return __builtin_bit_cast(u16, h);
}
__device__ __forceinline__ void cp16(const void* g, void* s){
  __builtin_amdgcn_global_load_lds(
    (const __attribute__((address_space(1))) unsigned int*)g,
    (__attribute__((address_space(3))) unsigned int*)s, 16, 0, 0);
}

// ---------------- K0b: x fp32 -> fp16 ----------------
// 22478848 elems, 8/thread, grid 10976 exact
__global__ __launch_bounds__(256) void k_cvt_x(const float* __restrict__ x,
                                               _Float16* __restrict__ xh){
  size_t i0 = ((size_t)blockIdx.x*256 + threadIdx.x)*8;
  float4 a = *(const float4*)(x + i0);
  float4 b = *(const float4*)(x + i0 + 4);
  ushort4 pk[2];
  pk[0].x=f2h(a.x); pk[0].y=f2h(a.y); pk[0].z=f2h(a.z); pk[0].w=f2h(a.w);
  pk[1].x=f2h(b.x); pk[1].y=f2h(b.y); pk[1].z=f2h(b.z); pk[1].w=f2h(b.w);
  *(uint4*)(xh + i0) = *(uint4*)&pk[0];
}

// ---------------- K0c: transpose+convert weights ----------------
__global__ __launch_bounds__(256) void k_cvt_w(const float* __restrict__ qw,
                                               const float* __restrict__ pw,
                                               _Float16* __restrict__ wT,
                                               _Float16* __restrict__ pwT){
  int idx = blockIdx.x*256 + threadIdx.x;
  int row = idx >> 5;
  int k0  = (idx & 31) << 3;
  const float* src; int stride; _Float16* dst;
  if (row < 768){ src = qw + row;        stride = 768; dst = wT  + (size_t)row*256 + k0; }
  else          { src = pw + (row-768);  stride = 256; dst = pwT + (size_t)(row-768)*256 + k0; }
  ushort4 pk[2];
  u16* p = (u16*)&pk[0];
  #pragma unroll
  for (int j=0;j<8;j++) p[j] = f2h(src[(size_t)(k0+j)*stride]);
  *(uint4*)dst = *(uint4*)&pk[0];
}

// ---------------- K0d: fused-layout f16 bias/mask tables ----------------
// thread = one (tbl_id, i, lc) row of 24 f16. tbl_id<64: mask w; >=64: bias h.
// layout: [tbl][i][lc][jt] with logical col = jt*16+lc; col>=NN or jt>=22 -> -inf
__global__ __launch_bounds__(256) void k_bm16(const float* __restrict__ mask,
                                              const float* __restrict__ tbl,
                                              const int* __restrict__ ridx,
                                              _Float16* __restrict__ m16,
                                              _Float16* __restrict__ b16){
  int idx = blockIdx.x*256 + threadIdx.x;
  const int tot = 72*NN*16;
  if (idx >= tot) return;
  int tb   = idx / (NN*16);
  int rest = idx - tb*(NN*16);
  int i  = rest >> 4;
  int lc = rest & 15;
  const u16 NEGINF = 0xFC00u;
  u16 buf[BMROW];
  if (tb < 64){
    const float* mrow = mask + ((size_t)tb*NN + i)*NN;
    #pragma unroll
    for (int jt=0;jt<BMROW;jt++){
      int col = jt*16 + lc;
      buf[jt] = (jt < 22 && col < NN) ? f2h(mrow[col]) : NEGINF;
    }
    uint4* dst = (uint4*)(m16 + (((size_t)tb*NN + i)*16 + lc)*BMROW);
    uint4* s = (uint4*)buf;
    dst[0]=s[0]; dst[1]=s[1]; dst[2]=s[2];
  } else {
    int h = tb - 64;
    const int* rrow = ridx + (size_t)i*NN;
    #pragma unroll
    for (int jt=0;jt<BMROW;jt++){
      int col = jt*16 + lc;
      buf[jt] = (jt < 22 && col < NN) ? f2h(tbl[rrow[col]*NH + h]) : NEGINF;
    }
    uint4* dst = (uint4*)(b16 + (((size_t)h*NN + i)*16 + lc)*BMROW);
    uint4* s = (uint4*)buf;
    dst[0]=s[0]; dst[1]=s[1]; dst[2]=s[2];
  }
}

// ---------------- K1: qkv GEMM via fp16 MFMA ----------------
__global__ __launch_bounds__(256,4) void k_qkv(const _Float16* __restrict__ xh,
                                               const _Float16* __restrict__ wT,
                                               const float* __restrict__ qkvb,
                                               u16* __restrict__ qws,
                                               u16* __restrict__ kws,
                                               u16* __restrict__ vws){
  const int nt = blockIdx.x % 6;
  const int mt = blockIdx.x / 6;
  const int m0 = mt*128, n0 = nt*128;
  __shared__ _Float16 As[128*32];
  __shared__ _Float16 Bs[128*32];
  const int t = threadIdx.x;
  const int wv = t >> 6, ln = t & 63, lc = ln & 15, lq = ln >> 4;
  const int wm = wv & 1, wn = wv >> 1;
  const _Float16* ga = xh + (size_t)(m0 + (t>>2))*CC + (t&3)*8;
  const _Float16* gb = wT + (size_t)(n0 + (t>>2))*CC + (t&3)*8;
  f4 acc[4][4];
  #pragma unroll
  for (int i=0;i<4;i++)
    #pragma unroll
    for (int j=0;j<4;j++) acc[i][j] = (f4){0.f,0.f,0.f,0.f};
  for (int kc=0; kc<256; kc+=32){
    __syncthreads();
    cp16(ga + kc,          As + t*8);
    cp16(ga + kc + 64*CC,  As + 2048 + t*8);
    cp16(gb + kc,          Bs + t*8);
    cp16(gb + kc + 64*CC,  Bs + 2048 + t*8);
    __syncthreads();
    h8 af[4], bf[4];
    #pragma unroll
    for (int mi=0;mi<4;mi++) af[mi] = *(const h8*)(As + (wm*64 + mi*16 + lc)*32 + lq*8);
    #pragma unroll
    for (int ni=0;ni<4;ni++) bf[ni] = *(const h8*)(Bs + (wn*64 + ni*16 + lc)*32 + lq*8);
    #pragma unroll
    for (int mi=0;mi<4;mi++)
      #pragma unroll
      for (int ni=0;ni<4;ni++)
        acc[mi][ni] = __builtin_amdgcn_mfma_f32_16x16x32_f16(af[mi], bf[ni], acc[mi][ni], 0,0,0);
  }
  float bias4[4];
  int   nidx[4];
  #pragma unroll
  for (int ni=0;ni<4;ni++){
    int n = n0 + wn*64 + ni*16 + lc;
    nidx[ni] = n;
    bias4[ni] = qkvb[n];
  }
  #pragma unroll
  for (int mi=0;mi<4;mi++){
    #pragma unroll
    for (int r=0;r<4;r++){
      int m = m0 + wm*64 + mi*16 + lq*4 + r;
      int b = m / NN;
      int i = m - b*NN;
      #pragma unroll
      for (int ni=0;ni<4;ni++){
        int n = nidx[ni];
        int s = n >> 8, h = (n >> 5) & 7, d = n & 31;
        size_t off = ((size_t)(b*NH + h)*NN + i)*HD + d;
        float val = acc[mi][ni][r] + bias4[ni];
        if      (s == 0) qws[off] = f2bf(val*SCALE_);
        else if (s == 1) kws[off] = f2bf(val);
        else             vws[off] = f2h(val);
      }
    }
  }
}

// ---------------- K2: MFMA flash attention ----------------
// grid = 2048 (b,h), block 256 (4 waves)
#define KSTR 36
#define VSTR 364
#define PSTR 36
__global__ __launch_bounds__(256,3) void k_attn(const u16* __restrict__ qws,
                                                const u16* __restrict__ kws,
                                                const u16* __restrict__ vws,
                                                const _Float16* __restrict__ m16,
                                                const _Float16* __restrict__ b16,
                                                u16* __restrict__ ctxh){
  __shared__ u16 Klds[352*KSTR];
  __shared__ u16 Vt[HD*VSTR];
  __shared__ _Float16 Pch[4][16*PSTR];
  const int bh = blockIdx.x;
  const int b = bh >> 3, h = bh & 7, w = b & (NWIN-1);
  const size_t kvbase = (size_t)bh * (NN*HD);
  const int t = threadIdx.x;
  for (int task = t; task < 352*4; task += 256){
    int j = task >> 2, d0 = (task & 3) << 3;
    uint4 val = {0u,0u,0u,0u};
    if (j < NN) val = *(const uint4*)(kws + kvbase + j*HD + d0);
    *(uint2*)&Klds[j*KSTR + d0]     = make_uint2(val.x, val.y);
    *(uint2*)&Klds[j*KSTR + d0 + 4] = make_uint2(val.z, val.w);
  }
  for (int task = t; task < 88*4; task += 256){
    int jg = task >> 2, d0 = (task & 3) << 3;
    int j0 = jg*4;
    uint4 r0={0,0,0,0}, r1={0,0,0,0}, r2={0,0,0,0}, r3={0,0,0,0};
    const u16* vsrc = vws + kvbase;
    if (j0   < NN) r0 = *(const uint4*)(vsrc + (size_t)(j0  )*HD + d0);
    if (j0+1 < NN) r1 = *(const uint4*)(vsrc + (size_t)(j0+1)*HD + d0);
    if (j0+2 < NN) r2 = *(const uint4*)(vsrc + (size_t)(j0+2)*HD + d0);
    if (j0+3 < NN) r3 = *(const uint4*)(vsrc + (size_t)(j0+3)*HD + d0);
    const u32* p0=(const u32*)&r0; const u32* p1=(const u32*)&r1;
    const u32* p2=(const u32*)&r2; const u32* p3=(const u32*)&r3;
    #pragma unroll
    for (int e=0;e<8;e++){
      int sh = (e&1)*16;
      ushort4 c4;
      c4.x = (u16)(p0[e>>1] >> sh);
      c4.y = (u16)(p1[e>>1] >> sh);
      c4.z = (u16)(p2[e>>1] >> sh);
      c4.w = (u16)(p3[e>>1] >> sh);
      *(ushort4*)&Vt[(d0+e)*VSTR + j0] = c4;
    }
  }
  __syncthreads();
  const int wv = t >> 6, ln = t & 63;
  const int lc = ln & 15, lq = ln >> 4;
  _Float16* pch = &Pch[wv][0];
  const f4 z4 = {0.f,0.f,0.f,0.f};
  for (int sub = wv; sub < 22; sub += 4){
    int qrow = sub*16 + lc; if (qrow > NN-1) qrow = NN-1;
    s8v qa = *(const s8v*)(qws + kvbase + (size_t)qrow*HD + lq*8);
    f4 acc[22];
    #pragma unroll
    for (int jt=0; jt<22; jt++){
      const u16* kp = &Klds[(jt*16+lc)*KSTR + lq*8];
      s4v k0 = *(const s4v*)kp;
      s4v k1 = *(const s4v*)(kp+4);
      s8v bk = {k0[0],k0[1],k0[2],k0[3],k1[0],k1[1],k1[2],k1[3]};
      acc[jt] = __builtin_amdgcn_mfma_f32_16x16x32_bf16(qa, bk, z4, 0,0,0);
    }
    float l[4];
    #pragma unroll
    for (int r=0;r<4;r++){
      int i = sub*16 + lq*4 + r; if (i > NN-1) i = NN-1;
      const _Float16* mp = m16 + (((size_t)w*NN + i)*16 + lc)*BMROW;
      const _Float16* bp = b16 + (((size_t)h*NN + i)*16 + lc)*BMROW;
      h8 m0 = *(const h8*)mp;
      h8 m1 = *(const h8*)(mp+8);
      h8 m2 = *(const h8*)(mp+16);
      h8 b0 = *(const h8*)bp;
      h8 b1 = *(const h8*)(bp+8);
      h8 b2 = *(const h8*)(bp+16);
      h8 s0 = m0 + b0;
      h8 s1 = m1 + b1;
      h8 s2 = m2 + b2;
      float mx0=-INFINITY, mx1=-INFINITY, mx2=-INFINITY, mx3=-INFINITY;
      #pragma unroll
      for (int jt=0; jt<22; jt++){
        float bmv = (float)(jt<8 ? s0[jt] : (jt<16 ? s1[jt-8] : s2[jt-16]));
        float sv = acc[jt][r] + bmv;
        acc[jt][r] = sv;
        if      ((jt&3)==0) mx0 = fmaxf(mx0, sv);
        else if ((jt&3)==1) mx1 = fmaxf(mx1, sv);
        else if ((jt&3)==2) mx2 = fmaxf(mx2, sv);
        else                mx3 = fmaxf(mx3, sv);
      }
      float mx = fmaxf(fmaxf(mx0,mx1), fmaxf(mx2,mx3));
      mx = fmaxf(mx, __shfl_xor(mx, 1));
      mx = fmaxf(mx, __shfl_xor(mx, 2));
      mx = fmaxf(mx, __shfl_xor(mx, 4));
      mx = fmaxf(mx, __shfl_xor(mx, 8));
      float mxl = mx * LOG2E_;
      float p0=0.f, p1=0.f, p2=0.f, p3=0.f;
      #pragma unroll
      for (int jt=0; jt<22; jt++){
        float p = exp2f(__builtin_fmaf(acc[jt][r], LOG2E_, -mxl));
        acc[jt][r] = p;
        if      ((jt&3)==0) p0 += p;
        else if ((jt&3)==1) p1 += p;
        else if ((jt&3)==2) p2 += p;
        else                p3 += p;
      }
      float s_ = (p0+p1)+(p2+p3);
      s_ += __shfl_xor(s_, 1);
      s_ += __shfl_xor(s_, 2);
      s_ += __shfl_xor(s_, 4);
      s_ += __shfl_xor(s_, 8);
      l[r] = s_;
    }
    f4 o0 = z4, o1 = z4;
    #pragma unroll
    for (int kt=0; kt<11; kt++){
      #pragma unroll
      for (int jp=0; jp<2; jp++){
        int jt = kt*2 + jp;
        #pragma unroll
        for (int r=0;r<4;r++)
          pch[(lq*4+r)*PSTR + jp*16 + lc] = (_Float16)acc[jt][r];
      }
      const _Float16* pap = pch + lc*PSTR + lq*8;
      h4 a0 = *(const h4*)pap;
      h4 a1 = *(const h4*)(pap+4);
      h8 pa = {a0[0],a0[1],a0[2],a0[3],a1[0],a1[1],a1[2],a1[3]};
      const _Float16* vp0 = (const _Float16*)&Vt[(lc   )*VSTR + kt*32 + lq*8];
      const _Float16* vp1 = (const _Float16*)&Vt[(lc+16)*VSTR + kt*32 + lq*8];
      h4 b00 = *(const h4*)vp0; h4 b01 = *(const h4*)(vp0+4);
      h4 b10 = *(const h4*)vp1; h4 b11 = *(const h4*)(vp1+4);
      h8 vb0 = {b00[0],b00[1],b00[2],b00[3],b01[0],b01[1],b01[2],b01[3]};
      h8 vb1 = {b10[0],b10[1],b10[2],b10[3],b11[0],b11[1],b11[2],b11[3]};
      o0 = __builtin_amdgcn_mfma_f32_16x16x32_f16(pa, vb0, o0, 0,0,0);
      o1 = __builtin_amdgcn_mfma_f32_16x16x32_f16(pa, vb1, o1, 0,0,0);
    }
    #pragma unroll
    for (int r=0;r<4;r++){
      int i = sub*16 + lq*4 + r;
      if (i < NN){
        float inv = __builtin_amdgcn_rcpf(l[r]);
        u16* op = ctxh + ((size_t)b*NN + i)*CC + h*HD;
        op[lc]    = f2h(o0[r]*inv);
        op[lc+16] = f2h(o1[r]*inv);
      }
    }
  }
}

// ---------------- K3: proj GEMM via fp16 MFMA ----------------
__global__ __launch_bounds__(256,4) void k_proj(const _Float16* __restrict__ ctxh,
                                                const _Float16* __restrict__ pwT,
                                                const float* __restrict__ pb,
                                                float* __restrict__ out){
  const int nt = blockIdx.x & 1;
  const int mt = blockIdx.x >> 1;
  const int m0 = mt*128, n0 = nt*128;
  __shared__ _Float16 As[128*32];
  __shared__ _Float16 Bs[128*32];
  const int t = threadIdx.x;
  const int wv = t >> 6, ln = t & 63, lc = ln & 15, lq = ln >> 4;
  const int wm = wv & 1, wn = wv >> 1;
  const _Float16* ga = ctxh + (size_t)(m0 + (t>>2))*CC + (t&3)*8;
  const _Float16* gb = pwT  + (size_t)(n0 + (t>>2))*CC + (t&3)*8;
  f4 acc[4][4];
  #pragma unroll
  for (int i=0;i<4;i++)
    #pragma unroll
    for (int j=0;j<4;j++) acc[i][j] = (f4){0.f,0.f,0.f,0.f};
  for (int kc=0; kc<256; kc+=32){
    __syncthreads();
    cp16(ga + kc,          As + t*8);
    cp16(ga + kc + 64*CC,  As + 2048 + t*8);
    cp16(gb + kc,          Bs + t*8);
    cp16(gb + kc + 64*CC,  Bs + 2048 + t*8);
    __syncthreads();
    h8 af[4], bf[4];
    #pragma unroll
    for (int mi=0;mi<4;mi++) af[mi] = *(const h8*)(As + (wm*64 + mi*16 + lc)*32 + lq*8);
    #pragma unroll
    for (int ni=0;ni<4;ni++) bf[ni] = *(const h8*)(Bs + (wn*64 + ni*16 + lc)*32 + lq*8);
    #pragma unroll
    for (int mi=0;mi<4;mi++)
      #pragma unroll
      for (int ni=0;ni<4;ni++)
        acc[mi][ni] = __builtin_amdgcn_mfma_f32_16x16x32_f16(af[mi], bf[ni], acc[mi][ni], 0,0,0);
  }
  float bias4[4];
  #pragma unroll
  for (int ni=0;ni<4;ni++) bias4[ni] = pb[n0 + wn*64 + ni*16 + lc];
  #pragma unroll
  for (int mi=0;mi<4;mi++){
    #pragma unroll
    for (int r=0;r<4;r++){
      int m = m0 + wm*64 + mi*16 + lq*4 + r;
      float* orow = out + (size_t)m*CC + n0 + wn*64;
      #pragma unroll
      for (int ni=0;ni<4;ni++)
        orow[ni*16 + lc] = acc[mi][ni][r] + bias4[ni];
    }
  }
}

extern "C" void kernel_launch(void* const* d_in, const int* in_sizes, int n_in,
                              void* d_out, int out_size, void* d_ws, size_t ws_size,
                              hipStream_t stream){
  (void)in_sizes; (void)n_in; (void)out_size; (void)ws_size;
  const float* x   = (const float*)d_in[0];
  const float* msk = (const float*)d_in[1];
  const float* qw  = (const float*)d_in[2];
  const float* qb  = (const float*)d_in[3];
  const float* pw  = (const float*)d_in[4];
  const float* pb  = (const float*)d_in[5];
  const float* tbl = (const float*)d_in[6];
  const int*   rix = (const int*)d_in[7];
  float* out = (float*)d_out;
  char* ws = (char*)d_ws;
  u16*      qws    = (u16*)(ws + OFF_Q);
  u16*      kws    = (u16*)(ws + OFF_K);
  u16*      vws    = (u16*)(ws + OFF_V);
  _Float16* xh     = (_Float16*)(ws + OFF_XH);
  _Float16* ctxh   = (_Float16*)(ws + OFF_CTXH);
  _Float16* wT     = (_Float16*)(ws + OFF_WT);
  _Float16* pwT    = (_Float16*)(ws + OFF_PWT);
  _Float16* m16    = (_Float16*)(ws + OFF_M16);
  _Float16* b16    = (_Float16*)(ws + OFF_B16);

  hipLaunchKernelGGL(k_cvt_x, dim3(10976), dim3(256), 0, stream, x, xh);
  hipLaunchKernelGGL(k_cvt_w, dim3(128), dim3(256), 0, stream, qw, pw, wT, pwT);
  hipLaunchKernelGGL(k_qkv,   dim3(686*6), dim3(256), 0, stream, xh, wT, qb, qws, kws, vws);
  // m16/b16 overwrite the xh region -> must run after k_qkv (stream-ordered)
  hipLaunchKernelGGL(k_bm16,  dim3((72*NN*16 + 255)/256), dim3(256), 0, stream, msk, tbl, rix, m16, b16);
  hipLaunchKernelGGL(k_attn,  dim3(NB*NH), dim3(256), 0, stream, qws, kws, vws, m16, b16, (u16*)ctxh);
  hipLaunchKernelGGL(k_proj,  dim3(686*2), dim3(256), 0, stream, ctxh, pwT, pb, out);
}